// Round 1
// baseline (710.299 us; speedup 1.0000x reference)
//
#include <hip/hip_runtime.h>
#include <hip/hip_bf16.h>

#define EPSF 1e-15f
#define MAXNF 0.99999f

__device__ __forceinline__ float wave_sum(float v) {
#pragma unroll
    for (int off = 32; off > 0; off >>= 1) v += __shfl_xor(v, off, 64);
    return v;
}

// 128-thread (2-wave) block sum; `red` is a 2-float LDS buffer.
__device__ __forceinline__ float blk128_sum(float v, float* red) {
    v = wave_sum(v);
    __syncthreads();
    if ((threadIdx.x & 63) == 0) red[threadIdx.x >> 6] = v;
    __syncthreads();
    return red[0] + red[1];
}

// ---------------- K1: RevIN statistics ----------------
__global__ __launch_bounds__(128) void k_revin(const float* __restrict__ x,
                                               float* __restrict__ mu_o,
                                               float* __restrict__ std_o) {
    int b = blockIdx.x, f = threadIdx.x;
    const float* xp = x + (size_t)b * 336 * 128 + f;
    float s = 0.f, s2 = 0.f;
    for (int l = 0; l < 336; ++l) {
        float v = xp[(size_t)l * 128];
        s += v; s2 += v * v;
    }
    float mu = s / 336.0f;
    float var = s2 / 336.0f - mu * mu;
    mu_o[b * 128 + f] = mu;
    std_o[b * 128 + f] = sqrtf(var + 1e-5f);
}

// ---------------- K2: encoder + vels + v_init + v0t (per row r=b*F+f) ----------------
__global__ __launch_bounds__(128) void k_encode(
    const float* __restrict__ x, const float* __restrict__ mu_i, const float* __restrict__ std_i,
    const float* __restrict__ revin_w, const float* __restrict__ revin_b,
    const float* __restrict__ W_enc, const float* __restrict__ b_enc,
    const float* __restrict__ W_vel, const float* __restrict__ b_vel,
    float* __restrict__ z0_o, float* __restrict__ v0t_o) {
    __shared__ float xl[336];
    __shared__ float red[2];
    __shared__ float vv[128];
    int r = blockIdx.x;
    int b = r >> 7, f = r & 127, d = threadIdx.x;
    float mu = mu_i[r], sd = std_i[r];
    float rw = revin_w[f], rb = revin_b[f];
    const float* xp = x + (size_t)b * 336 * 128 + f;
    for (int l = d; l < 336; l += 128)
        xl[l] = (xp[(size_t)l * 128] - mu) / sd * rw + rb;
    __syncthreads();

    // normalized weights for v_init: w_i = 0.9^(12-i)/sum, extra /13 from jnp.mean
    float wsum = 0.f;
    { float p = 1.f; for (int k = 0; k < 13; ++k) { wsum += p; p *= 0.9f; } }

    float be = b_enc[d];
    float zp = 0.f, szp = 0.f;   // z_{n-1}[d], |z_{n-1}|^2
    float vacc = 0.f;            // v_init[d]
    for (int n = 0; n < 14; ++n) {
        float u = be;
#pragma unroll
        for (int s = 0; s < 24; ++s) u += xl[n * 24 + s] * W_enc[s * 128 + d];
        float ssq = blk128_sum(u * u, red);
        float nn = sqrtf(fmaxf(ssq, EPSF));
        float th = tanhf(nn);
        float z = th / nn * u;
        float sz = th * th;
        if (th > MAXNF) { z *= MAXNF / th; sz = MAXNF * MAXNF; }  // projx
        if (n > 0) {
            // vel = logmap(zp, z):  u2 = mobius_add(-zp, z)
            float xy = blk128_sum(-zp * z, red);
            float den = fmaxf(1.f + 2.f * xy + szp * sz, EPSF);
            float num = (1.f + 2.f * xy + sz) * (-zp) + (1.f - szp) * z;
            float uu = num / den;
            float usq = blk128_sum(uu * uu, red);
            float un = sqrtf(fmaxf(usq, EPSF));
            float art = atanhf(fminf(un, 1.f - 1e-7f));
            float two_over_lam = fmaxf(1.f - szp, EPSF);  // 2/lam(x)
            float vel = two_over_lam * art / un * uu;
            float wi = powf(0.9f, (float)(13 - n)) / (wsum * 13.f);
            vacc += wi * vel;
        }
        zp = z; szp = sz;
    }

    // mobius_matvec(W_vel, v_init)
    vv[d] = vacc;
    float xnsq = blk128_sum(vacc * vacc, red);  // also syncs vv
    float mx = 0.f;
    const float* wr = W_vel + (size_t)d * 128;
#pragma unroll 8
    for (int j = 0; j < 128; ++j) mx += wr[j] * vv[j];
    float mxnsq = blk128_sum(mx * mx, red);
    float xn = sqrtf(fmaxf(xnsq, EPSF));
    float mxn = sqrtf(fmaxf(mxnsq, EPSF));
    float artx = atanhf(fminf(xn, 1.f - 1e-7f));
    float tm = tanhf(mxn / xn * artx);
    float m = tm * mx / mxn;
    float sm = tm * tm;

    // c = expmap0(b_vel)
    float cb = b_vel[d];
    float cbsq = blk128_sum(cb * cb, red);
    float ncb = sqrtf(fmaxf(cbsq, EPSF));
    float tc = tanhf(ncb);
    float c = tc / ncb * cb;
    float sc = tc * tc;

    // mobius_add(m, c) -> projx
    float xy2 = blk128_sum(m * c, red);
    float den2 = fmaxf(1.f + 2.f * xy2 + sm * sc, EPSF);
    float v0 = ((1.f + 2.f * xy2 + sc) * m + (1.f - sm) * c) / den2;
    float v0sq = blk128_sum(v0 * v0, red);
    float nv0 = sqrtf(fmaxf(v0sq, EPSF));
    if (nv0 > MAXNF) v0 *= MAXNF / nv0;

    z0_o[(size_t)r * 128 + d] = zp;   // z[:, -1, :]
    v0t_o[(size_t)r * 128 + d] = v0;
}

// ---------------- K3: futures -> tan (per row r, all 8 t) ----------------
__global__ __launch_bounds__(128) void k_future(
    const float* __restrict__ z0_i, const float* __restrict__ v0t_i,
    const float* __restrict__ step_sizes, float* __restrict__ tan_o) {
    __shared__ float red[2];
    int r = blockIdx.x, d = threadIdx.x;
    float z0 = z0_i[(size_t)r * 128 + d];
    float vd = v0t_i[(size_t)r * 128 + d];
    float step = 1.f / (1.f + expf(-step_sizes[0]));
    float x2 = blk128_sum(z0 * z0, red);
    float lam = 2.f / fmaxf(1.f - x2, EPSF);
    for (int t = 1; t <= 8; ++t) {
        float v = step * (float)t * vd;
        float nsq = blk128_sum(v * v, red);
        float n = sqrtf(fmaxf(nsq, EPSF));
        float sec = tanhf(lam * n * 0.5f) * v / n;
        float y2 = blk128_sum(sec * sec, red);
        float xy = blk128_sum(z0 * sec, red);
        float den = fmaxf(1.f + 2.f * xy + x2 * y2, EPSF);
        float res = ((1.f + 2.f * xy + y2) * z0 + (1.f - x2) * sec) / den;
        float rsq = blk128_sum(res * res, red);
        float nr = sqrtf(fmaxf(rsq, EPSF));
        if (nr > MAXNF) { res *= MAXNF / nr; nr = MAXNF; }  // projx
        float art = atanhf(fminf(nr, 1.f - 1e-7f));         // logmap0
        tan_o[((size_t)r * 8 + (t - 1)) * 128 + d] = art / nr * res;
    }
}

// ---------------- K4: head GEMMs + denorm + transposed store ----------------
__global__ __launch_bounds__(256) void k_head(
    const float* __restrict__ tanb, const float* __restrict__ W1, const float* __restrict__ b1,
    const float* __restrict__ W2, const float* __restrict__ b2,
    const float* __restrict__ mu_i, const float* __restrict__ std_i,
    const float* __restrict__ revin_w, const float* __restrict__ revin_b,
    float* __restrict__ out) {
    __shared__ __align__(16) float sT[32][128];   // 16 KB
    __shared__ __align__(16) float sH[32][260];   // 33.3 KB (pad 260: float4-aligned, banks spread)
    int row0 = blockIdx.x * 32;
    int tid = threadIdx.x;
    for (int i = tid; i < 32 * 128; i += 256)
        sT[i >> 7][i & 127] = tanb[(size_t)row0 * 128 + i];
    __syncthreads();

    // h[r][tid] = relu(b1 + sum_d tan[r][d]*W1[d][tid])
    float acc[32];
    float bj = b1[tid];
#pragma unroll
    for (int rr = 0; rr < 32; ++rr) acc[rr] = bj;
    for (int d4 = 0; d4 < 32; ++d4) {
        float w0 = W1[(4 * d4 + 0) * 256 + tid];
        float w1 = W1[(4 * d4 + 1) * 256 + tid];
        float w2 = W1[(4 * d4 + 2) * 256 + tid];
        float w3 = W1[(4 * d4 + 3) * 256 + tid];
#pragma unroll
        for (int rr = 0; rr < 32; ++rr) {
            float4 tv = *(const float4*)&sT[rr][4 * d4];
            acc[rr] += tv.x * w0 + tv.y * w1 + tv.z * w2 + tv.w * w3;
        }
    }
#pragma unroll
    for (int rr = 0; rr < 32; ++rr) sH[rr][tid] = fmaxf(acc[rr], 0.f);
    __syncthreads();

    // out[r][s] = b2[s] + sum_j h[r][j]*W2[j][s], then denorm + transposed store
    if (tid < 192) {
        int s = tid % 24, rbase = tid / 24;
        for (int pass = 0; pass < 4; ++pass) {
            int rr = pass * 8 + rbase;
            float a = b2[s];
            for (int j4 = 0; j4 < 64; ++j4) {
                float4 h4 = *(const float4*)&sH[rr][4 * j4];
                a += h4.x * W2[(4 * j4 + 0) * 24 + s];
                a += h4.y * W2[(4 * j4 + 1) * 24 + s];
                a += h4.z * W2[(4 * j4 + 2) * 24 + s];
                a += h4.w * W2[(4 * j4 + 3) * 24 + s];
            }
            int row = row0 + rr;
            int rI = row >> 3, tt = row & 7;
            int b = rI >> 7, f = rI & 127;
            float v = (a - revin_b[f]) / revin_w[f] * std_i[rI] + mu_i[rI];
            out[((size_t)b * 192 + (tt * 24 + s)) * 128 + f] = v;
        }
    }
}

extern "C" void kernel_launch(void* const* d_in, const int* in_sizes, int n_in,
                              void* d_out, int out_size, void* d_ws, size_t ws_size,
                              hipStream_t stream) {
    (void)in_sizes; (void)n_in; (void)out_size; (void)ws_size;
    const float* x          = (const float*)d_in[0];
    const float* revin_w    = (const float*)d_in[1];
    const float* revin_b    = (const float*)d_in[2];
    const float* W_enc      = (const float*)d_in[3];
    const float* b_enc      = (const float*)d_in[4];
    const float* W_vel      = (const float*)d_in[5];
    const float* b_vel      = (const float*)d_in[6];
    const float* step_sizes = (const float*)d_in[7];
    const float* W1         = (const float*)d_in[8];
    const float* b1         = (const float*)d_in[9];
    const float* W2         = (const float*)d_in[10];
    const float* b2         = (const float*)d_in[11];
    float* out = (float*)d_out;

    float* mu   = (float*)d_ws;             // 16384
    float* sd   = mu + 16384;               // 16384
    float* z0   = sd + 16384;               // 16384*128
    float* v0t  = z0 + 16384 * 128;         // 16384*128
    float* tanb = v0t + 16384 * 128;        // 131072*128  (~67 MB)

    k_revin<<<dim3(128), dim3(128), 0, stream>>>(x, mu, sd);
    k_encode<<<dim3(16384), dim3(128), 0, stream>>>(x, mu, sd, revin_w, revin_b,
                                                    W_enc, b_enc, W_vel, b_vel, z0, v0t);
    k_future<<<dim3(16384), dim3(128), 0, stream>>>(z0, v0t, step_sizes, tanb);
    k_head<<<dim3(4096), dim3(256), 0, stream>>>(tanb, W1, b1, W2, b2,
                                                 mu, sd, revin_w, revin_b, out);
}

// Round 2
// 321.982 us; speedup vs baseline: 2.2060x; 2.2060x over previous
//
#include <hip/hip_runtime.h>
#include <hip/hip_bf16.h>

#define EPSF 1e-15f
#define MAXNF 0.99999f

typedef __attribute__((ext_vector_type(8))) short short8v;
typedef __attribute__((ext_vector_type(4))) float f32x4;

__device__ __forceinline__ float wave_sum(float v) {
#pragma unroll
    for (int off = 32; off > 0; off >>= 1) v += __shfl_xor(v, off, 64);
    return v;
}

// fp32 -> bf16 RNE
__device__ __forceinline__ ushort f2bf(float f) {
    uint32_t u = __float_as_uint(f);
    uint32_t r = (u + 0x7fffu + ((u >> 16) & 1u)) >> 16;
    return (ushort)r;
}

// ---------------- K0: prep — W1^T/W2^T to bf16, c = expmap0(b_vel) ----------------
__global__ __launch_bounds__(256) void k_prep(
    const float* __restrict__ W1, const float* __restrict__ W2,
    const float* __restrict__ b_vel,
    ushort* __restrict__ W1t, ushort* __restrict__ W2tp,
    float* __restrict__ cvec, float* __restrict__ scp) {
    int bid = blockIdx.x, tid = threadIdx.x;
    if (bid == 0) {
        __shared__ float red[4];
        float v = (tid < 128) ? b_vel[tid] : 0.f;
        float p = wave_sum(v * v);
        if ((tid & 63) == 0) red[tid >> 6] = p;
        __syncthreads();
        float ssq = red[0] + red[1] + red[2] + red[3];
        float nn = sqrtf(fmaxf(ssq, EPSF));
        float th = tanhf(nn);
        if (tid < 128) cvec[tid] = th / nn * v;
        if (tid == 0) scp[0] = th * th;
    } else if (bid <= 128) {
        int idx = (bid - 1) * 256 + tid;      // n*128 + k
        int n = idx >> 7, k = idx & 127;
        W1t[idx] = f2bf(W1[k * 256 + n]);
    } else {
        int idx = (bid - 129) * 256 + tid;    // s*256 + j  (s padded to 32)
        int s = idx >> 8, j = idx & 255;
        W2tp[idx] = (s < 24) ? f2bf(W2[j * 24 + s]) : (ushort)0;
    }
}

// ---------------- K1: RevIN stats + normalized transpose xnT[r=b*128+f][l] ----------------
__global__ __launch_bounds__(256) void k_stats_transpose(
    const float* __restrict__ x, const float* __restrict__ revin_w, const float* __restrict__ revin_b,
    float* __restrict__ mu_o, float* __restrict__ sd_o, float* __restrict__ xnT) {
    __shared__ float Tt[32][129];
    __shared__ float ps[2][128], ps2[2][128];
    __shared__ float sscale[128], sshift[128];
    int b = blockIdx.x, tid = threadIdx.x;
    int f = tid & 127, half = tid >> 7;
    const float* xp = x + ((size_t)b * 336 + half * 168) * 128 + f;
    float s = 0.f, s2 = 0.f;
    for (int l = 0; l < 168; ++l) { float v = xp[(size_t)l * 128]; s += v; s2 += v * v; }
    ps[half][f] = s; ps2[half][f] = s2;
    __syncthreads();
    if (tid < 128) {
        float S = ps[0][f] + ps[1][f], S2 = ps2[0][f] + ps2[1][f];
        float m = S / 336.f;
        float var = S2 / 336.f - m * m;
        float sd = sqrtf(var + 1e-5f);
        mu_o[b * 128 + f] = m; sd_o[b * 128 + f] = sd;
        float sc = revin_w[f] / sd;
        sscale[f] = sc; sshift[f] = revin_b[f] - m * sc;
    }
    __syncthreads();
    for (int c0 = 0; c0 < 336; c0 += 32) {
        int nl = min(32, 336 - c0);
        for (int i = half; i < nl; i += 2)
            Tt[i][f] = x[((size_t)b * 336 + c0 + i) * 128 + f] * sscale[f] + sshift[f];
        __syncthreads();
        int ll = tid & 31, fr0 = tid >> 5;
        if (ll < nl)
            for (int fr = fr0; fr < 128; fr += 8)
                xnT[((size_t)(b * 128 + fr)) * 352 + c0 + ll] = Tt[ll][fr];
        __syncthreads();
    }
}

// ---------------- K2: encoder + vels + v_init  (wave-per-row, 2 elems/lane) ----------------
__global__ __launch_bounds__(256) void k_encode(
    const float* __restrict__ xnT,
    const float* __restrict__ W_enc, const float* __restrict__ b_enc,
    float* __restrict__ z0_o, float* __restrict__ vinit_o) {
    __shared__ float xl[4][344];
    int wid = threadIdx.x >> 6, lane = threadIdx.x & 63;
    int r = blockIdx.x * 4 + wid;
    const float* xp = xnT + (size_t)r * 352;
    for (int l = lane; l < 336; l += 64) xl[wid][l] = xp[l];
    float we0[24], we1[24];
#pragma unroll
    for (int s = 0; s < 24; ++s) {
        we0[s] = W_enc[s * 128 + lane];
        we1[s] = W_enc[s * 128 + lane + 64];
    }
    float be0 = b_enc[lane], be1 = b_enc[lane + 64];
    __syncthreads();

    float wsum = 0.f;
    { float p = 1.f; for (int k = 0; k < 13; ++k) { wsum += p; p *= 0.9f; } }
    float wi; { float p = 1.f; for (int k = 0; k < 12; ++k) p *= 0.9f; wi = p / (wsum * 13.f); }

    float zp0 = 0.f, zp1 = 0.f, szp = 0.f, vac0 = 0.f, vac1 = 0.f;
    for (int n = 0; n < 14; ++n) {
        float u0 = be0, u1 = be1;
        const float* xr = &xl[wid][n * 24];
#pragma unroll
        for (int s = 0; s < 24; ++s) { float xv = xr[s]; u0 += xv * we0[s]; u1 += xv * we1[s]; }
        float ssq = wave_sum(u0 * u0 + u1 * u1);
        float nn = sqrtf(fmaxf(ssq, EPSF));
        float th = tanhf(nn);
        float scz = th / nn;
        float z0v = scz * u0, z1v = scz * u1;
        float sz = th * th;
        if (th > MAXNF) { float fc = MAXNF / th; z0v *= fc; z1v *= fc; sz = MAXNF * MAXNF; }
        if (n > 0) {
            float xy = wave_sum(-(zp0 * z0v + zp1 * z1v));
            float den = fmaxf(1.f + 2.f * xy + szp * sz, EPSF);
            float a1 = 1.f + 2.f * xy + sz, a2 = 1.f - szp;
            float uu0 = (a1 * (-zp0) + a2 * z0v) / den;
            float uu1 = (a1 * (-zp1) + a2 * z1v) / den;
            float usq = wave_sum(uu0 * uu0 + uu1 * uu1);
            float un = sqrtf(fmaxf(usq, EPSF));
            float art = atanhf(fminf(un, 1.f - 1e-7f));
            float fac = fmaxf(1.f - szp, EPSF) * art / un * wi;
            vac0 += fac * uu0; vac1 += fac * uu1;
            wi *= (1.f / 0.9f);
        }
        zp0 = z0v; zp1 = z1v; szp = sz;
    }
    z0_o[(size_t)r * 128 + lane] = zp0;
    z0_o[(size_t)r * 128 + lane + 64] = zp1;
    vinit_o[(size_t)r * 128 + lane] = vac0;
    vinit_o[(size_t)r * 128 + lane + 64] = vac1;
}

// ---------------- K3: mx = v_init @ W_vel^T  (8 rows/block, 4 rows/thread) ----------------
__global__ __launch_bounds__(256) void k_matvec(
    const float* __restrict__ vinit, const float* __restrict__ W_vel,
    float* __restrict__ mx_o) {
    __shared__ float vv[8][128];
    int tid = threadIdx.x;
    int r0 = blockIdx.x * 8;
    for (int i = tid; i < 1024; i += 256) vv[i >> 7][i & 127] = vinit[(size_t)r0 * 128 + i];
    __syncthreads();
    int d = tid & 127, h = tid >> 7;
    float m0 = 0.f, m1 = 0.f, m2 = 0.f, m3 = 0.f;
    const float4* wr = reinterpret_cast<const float4*>(W_vel + (size_t)d * 128);
    const float4* v0 = reinterpret_cast<const float4*>(vv[h * 4 + 0]);
    const float4* v1 = reinterpret_cast<const float4*>(vv[h * 4 + 1]);
    const float4* v2 = reinterpret_cast<const float4*>(vv[h * 4 + 2]);
    const float4* v3 = reinterpret_cast<const float4*>(vv[h * 4 + 3]);
#pragma unroll 8
    for (int j = 0; j < 32; ++j) {
        float4 w = wr[j];
        float4 a = v0[j]; m0 += w.x * a.x + w.y * a.y + w.z * a.z + w.w * a.w;
        float4 bb = v1[j]; m1 += w.x * bb.x + w.y * bb.y + w.z * bb.z + w.w * bb.w;
        float4 c = v2[j]; m2 += w.x * c.x + w.y * c.y + w.z * c.z + w.w * c.w;
        float4 e = v3[j]; m3 += w.x * e.x + w.y * e.y + w.z * e.z + w.w * e.w;
    }
    mx_o[(size_t)(r0 + h * 4 + 0) * 128 + d] = m0;
    mx_o[(size_t)(r0 + h * 4 + 1) * 128 + d] = m1;
    mx_o[(size_t)(r0 + h * 4 + 2) * 128 + d] = m2;
    mx_o[(size_t)(r0 + h * 4 + 3) * 128 + d] = m3;
}

// ---------------- K4: v0t tail + futures -> tan (bf16)  (wave-per-row) ----------------
__global__ __launch_bounds__(256) void k_future(
    const float* __restrict__ z0_i, const float* __restrict__ vinit, const float* __restrict__ mx_i,
    const float* __restrict__ cvec, const float* __restrict__ scp,
    const float* __restrict__ step_sizes, ushort* __restrict__ tanb) {
    int wid = threadIdx.x >> 6, lane = threadIdx.x & 63;
    int r = blockIdx.x * 4 + wid;
    size_t base = (size_t)r * 128;
    float vi0 = vinit[base + lane], vi1 = vinit[base + lane + 64];
    float mx0 = mx_i[base + lane], mx1 = mx_i[base + lane + 64];
    // mobius_matvec tail
    float xn2 = wave_sum(vi0 * vi0 + vi1 * vi1);
    float mxn2 = wave_sum(mx0 * mx0 + mx1 * mx1);
    float xn = sqrtf(fmaxf(xn2, EPSF)), mxn = sqrtf(fmaxf(mxn2, EPSF));
    float artx = atanhf(fminf(xn, 1.f - 1e-7f));
    float tm = tanhf(mxn / xn * artx);
    float scm = tm / mxn;
    float m0 = scm * mx0, m1 = scm * mx1;
    float sm = tm * tm;
    // mobius_add(m, c) -> projx
    float c0 = cvec[lane], c1 = cvec[lane + 64];
    float scc = scp[0];
    float xy2 = wave_sum(m0 * c0 + m1 * c1);
    float den2 = fmaxf(1.f + 2.f * xy2 + sm * scc, EPSF);
    float a1 = 1.f + 2.f * xy2 + scc, a2 = 1.f - sm;
    float v00 = (a1 * m0 + a2 * c0) / den2;
    float v01 = (a1 * m1 + a2 * c1) / den2;
    float v0sq = wave_sum(v00 * v00 + v01 * v01);
    float nv0 = sqrtf(fmaxf(v0sq, EPSF));
    if (nv0 > MAXNF) { float fc = MAXNF / nv0; v00 *= fc; v01 *= fc; }
    // futures
    float z00 = z0_i[base + lane], z01 = z0_i[base + lane + 64];
    float x2 = wave_sum(z00 * z00 + z01 * z01);
    float lam = 2.f / fmaxf(1.f - x2, EPSF);
    float step = 1.f / (1.f + expf(-step_sizes[0]));
    for (int t = 1; t <= 8; ++t) {
        float v0 = step * (float)t * v00, v1 = step * (float)t * v01;
        float nsq = wave_sum(v0 * v0 + v1 * v1);
        float n = sqrtf(fmaxf(nsq, EPSF));
        float th2 = tanhf(lam * n * 0.5f);
        float sf = th2 / n;
        float s0 = sf * v0, s1 = sf * v1;
        float y2 = th2 * th2;
        float xy = wave_sum(z00 * s0 + z01 * s1);
        float den = fmaxf(1.f + 2.f * xy + x2 * y2, EPSF);
        float b1c = 1.f + 2.f * xy + y2, b2c = 1.f - x2;
        float r0v = (b1c * z00 + b2c * s0) / den;
        float r1v = (b1c * z01 + b2c * s1) / den;
        float rsq = wave_sum(r0v * r0v + r1v * r1v);
        float nr = sqrtf(fmaxf(rsq, EPSF));
        if (nr > MAXNF) { float fc = MAXNF / nr; r0v *= fc; r1v *= fc; nr = MAXNF; }
        float art = atanhf(fminf(nr, 1.f - 1e-7f));
        float tf = art / nr;
        size_t ob = ((size_t)r * 8 + (t - 1)) * 128;
        tanb[ob + lane] = f2bf(tf * r0v);
        tanb[ob + lane + 64] = f2bf(tf * r1v);
    }
}

// ---------------- K5: head via bf16 MFMA (64 rows/block, 16 rows/wave) ----------------
__global__ __launch_bounds__(256) void k_head(
    const ushort* __restrict__ tanb, const ushort* __restrict__ W1t, const float* __restrict__ b1,
    const ushort* __restrict__ W2tp, const float* __restrict__ b2,
    const float* __restrict__ mu_i, const float* __restrict__ std_i,
    const float* __restrict__ revin_w, const float* __restrict__ revin_b,
    float* __restrict__ out) {
    __shared__ __align__(16) ushort hs[4][16][264];
    int wid = threadIdx.x >> 6, lane = threadIdx.x & 63;
    int r0 = blockIdx.x * 64 + wid * 16;
    int lrow = lane & 15, lk = lane >> 4;
    // A fragments: tan rows r0..r0+15, K=128
    short8v A[4];
    const ushort* tp = tanb + (size_t)(r0 + lrow) * 128 + lk * 8;
#pragma unroll
    for (int kk = 0; kk < 4; ++kk) A[kk] = *reinterpret_cast<const short8v*>(tp + kk * 32);
    f32x4 acc[16];
#pragma unroll
    for (int nt = 0; nt < 16; ++nt) acc[nt] = (f32x4)(0.f);
#pragma unroll
    for (int nt = 0; nt < 16; ++nt) {
        const ushort* wp = W1t + (size_t)(nt * 16 + lrow) * 128 + lk * 8;
#pragma unroll
        for (int kk = 0; kk < 4; ++kk) {
            short8v B = *reinterpret_cast<const short8v*>(wp + kk * 32);
            acc[nt] = __builtin_amdgcn_mfma_f32_16x16x32_bf16(A[kk], B, acc[nt], 0, 0, 0);
        }
    }
    // bias + relu -> LDS (bf16)
#pragma unroll
    for (int nt = 0; nt < 16; ++nt) {
        float bv = b1[nt * 16 + lrow];
#pragma unroll
        for (int j = 0; j < 4; ++j) {
            float h = fmaxf(acc[nt][j] + bv, 0.f);
            hs[wid][lk * 4 + j][nt * 16 + lrow] = f2bf(h);
        }
    }
    __syncthreads();
    // GEMM2: h[16x256] @ W2tp^T -> 16x32 (cols 0..23 valid)
    f32x4 acc2[2];
    acc2[0] = (f32x4)(0.f); acc2[1] = (f32x4)(0.f);
#pragma unroll
    for (int kk = 0; kk < 8; ++kk) {
        short8v Ah = *reinterpret_cast<const short8v*>(&hs[wid][lrow][kk * 32 + lk * 8]);
#pragma unroll
        for (int nt = 0; nt < 2; ++nt) {
            short8v B = *reinterpret_cast<const short8v*>(W2tp + (size_t)(nt * 16 + lrow) * 256 + kk * 32 + lk * 8);
            acc2[nt] = __builtin_amdgcn_mfma_f32_16x16x32_bf16(Ah, B, acc2[nt], 0, 0, 0);
        }
    }
    // epilogue: +b2, denorm, transposed scatter store
#pragma unroll
    for (int nt = 0; nt < 2; ++nt) {
        int col = nt * 16 + lrow;
        if (col < 24) {
            float b2v = b2[col];
#pragma unroll
            for (int j = 0; j < 4; ++j) {
                int row = r0 + lk * 4 + j;
                int rI = row >> 3, tt = row & 7;
                int bb = rI >> 7, f = rI & 127;
                float v = acc2[nt][j] + b2v;
                v = (v - revin_b[f]) / revin_w[f] * std_i[rI] + mu_i[rI];
                out[((size_t)bb * 192 + tt * 24 + col) * 128 + f] = v;
            }
        }
    }
}

extern "C" void kernel_launch(void* const* d_in, const int* in_sizes, int n_in,
                              void* d_out, int out_size, void* d_ws, size_t ws_size,
                              hipStream_t stream) {
    (void)in_sizes; (void)n_in; (void)out_size; (void)ws_size;
    const float* x          = (const float*)d_in[0];
    const float* revin_w    = (const float*)d_in[1];
    const float* revin_b    = (const float*)d_in[2];
    const float* W_enc      = (const float*)d_in[3];
    const float* b_enc      = (const float*)d_in[4];
    const float* W_vel      = (const float*)d_in[5];
    const float* b_vel      = (const float*)d_in[6];
    const float* step_sizes = (const float*)d_in[7];
    const float* W1         = (const float*)d_in[8];
    const float* b1         = (const float*)d_in[9];
    const float* W2         = (const float*)d_in[10];
    const float* b2         = (const float*)d_in[11];
    float* out = (float*)d_out;

    float* wsf = (float*)d_ws;
    float* mu    = wsf;                       // 16384
    float* sd    = mu + 16384;                // 16384
    float* xnT   = sd + 16384;                // 16384*352
    float* z0    = xnT + (size_t)16384 * 352; // 16384*128
    float* vinit = z0 + (size_t)16384 * 128;
    float* mx    = vinit + (size_t)16384 * 128;
    float* cvec  = mx + (size_t)16384 * 128;  // 128
    float* scp   = cvec + 128;                // 1 (pad 64)
    ushort* W1t  = (ushort*)(scp + 64);       // 32768 bf16
    ushort* W2tp = W1t + 32768;               // 8192 bf16
    ushort* tanb = W2tp + 8192;               // 131072*128 bf16

    k_prep<<<dim3(161), dim3(256), 0, stream>>>(W1, W2, b_vel, W1t, W2tp, cvec, scp);
    k_stats_transpose<<<dim3(128), dim3(256), 0, stream>>>(x, revin_w, revin_b, mu, sd, xnT);
    k_encode<<<dim3(4096), dim3(256), 0, stream>>>(xnT, W_enc, b_enc, z0, vinit);
    k_matvec<<<dim3(2048), dim3(256), 0, stream>>>(vinit, W_vel, mx);
    k_future<<<dim3(4096), dim3(256), 0, stream>>>(z0, vinit, mx, cvec, scp, step_sizes, tanb);
    k_head<<<dim3(2048), dim3(256), 0, stream>>>(tanb, W1t, b1, W2tp, b2,
                                                 mu, sd, revin_w, revin_b, out);
}

// Round 3
// 237.884 us; speedup vs baseline: 2.9859x; 1.3535x over previous
//
#include <hip/hip_runtime.h>
#include <hip/hip_bf16.h>

#define EPSF 1e-15f
#define MAXNF 0.99999f

typedef __attribute__((ext_vector_type(8))) short short8v;
typedef __attribute__((ext_vector_type(8))) ushort ushort8v;
typedef __attribute__((ext_vector_type(4))) float f32x4;

__device__ __forceinline__ float wave_sum(float v) {
#pragma unroll
    for (int off = 32; off > 0; off >>= 1) v += __shfl_xor(v, off, 64);
    return v;
}
__device__ __forceinline__ float rcpf(float x) { return __builtin_amdgcn_rcpf(x); }
// x >= 0; series guard avoids (1-e) cancellation at small x
__device__ __forceinline__ float tanh_g(float x) {
    if (x < 0.03f) return x * (1.f - 0.33333333f * x * x);
    float e = __expf(-2.f * x);
    return (1.f - e) * rcpf(1.f + e);
}
// 0 <= x <= 1-1e-7
__device__ __forceinline__ float atanh_g(float x) {
    if (x < 0.03f) return x * (1.f + 0.33333333f * x * x);
    return 0.5f * __logf((1.f + x) * rcpf(1.f - x));
}
__device__ __forceinline__ ushort f2bf(float f) {
    uint32_t u = __float_as_uint(f);
    uint32_t r = (u + 0x7fffu + ((u >> 16) & 1u)) >> 16;
    return (ushort)r;
}
__device__ __forceinline__ float bf2f(ushort u) { return __uint_as_float(((uint32_t)u) << 16); }

// ---------------- K0: prep — W1^T/W2^T to bf16, c = expmap0(b_vel) ----------------
__global__ __launch_bounds__(256) void k_prep(
    const float* __restrict__ W1, const float* __restrict__ W2,
    const float* __restrict__ b_vel,
    ushort* __restrict__ W1t, ushort* __restrict__ W2tp,
    float* __restrict__ cvec, float* __restrict__ scp) {
    int bid = blockIdx.x, tid = threadIdx.x;
    if (bid == 0) {
        __shared__ float red[4];
        float v = (tid < 128) ? b_vel[tid] : 0.f;
        float p = wave_sum(v * v);
        if ((tid & 63) == 0) red[tid >> 6] = p;
        __syncthreads();
        float ssq = red[0] + red[1] + red[2] + red[3];
        float nn = sqrtf(fmaxf(ssq, EPSF));
        float th = tanhf(nn);
        if (tid < 128) cvec[tid] = th / nn * v;
        if (tid == 0) scp[0] = th * th;
    } else if (bid <= 128) {
        int idx = (bid - 1) * 256 + tid;      // n*128 + k
        int n = idx >> 7, k = idx & 127;
        W1t[idx] = f2bf(W1[k * 256 + n]);
    } else {
        int idx = (bid - 129) * 256 + tid;    // s*256 + j  (s padded to 32)
        int s = idx >> 8, j = idx & 255;
        W2tp[idx] = (s < 24) ? f2bf(W2[j * 24 + s]) : (ushort)0;
    }
}

// ---------------- K1: RevIN stats -> norm coeffs (sc,sh) + denorm coeffs (osc,osh) ----------------
__global__ __launch_bounds__(1024) void k_stats(
    const float* __restrict__ x, const float* __restrict__ revin_w, const float* __restrict__ revin_b,
    float* __restrict__ sc_o, float* __restrict__ sh_o,
    float* __restrict__ osc_o, float* __restrict__ osh_o) {
    __shared__ float ps[8][128], ps2[8][128];
    int b = blockIdx.x, tid = threadIdx.x;
    int f = tid & 127, half = tid >> 7;   // 8 L-slices of 42
    const float* xp = x + ((size_t)b * 336 + half * 42) * 128 + f;
    float s = 0.f, s2 = 0.f;
    for (int l = 0; l < 42; ++l) { float v = xp[(size_t)l * 128]; s += v; s2 += v * v; }
    ps[half][f] = s; ps2[half][f] = s2;
    __syncthreads();
    if (tid < 128) {
        float S = 0.f, S2 = 0.f;
#pragma unroll
        for (int h = 0; h < 8; ++h) { S += ps[h][f]; S2 += ps2[h][f]; }
        float m = S * (1.f / 336.f);
        float var = S2 * (1.f / 336.f) - m * m;
        float sd = sqrtf(var + 1e-5f);
        int r = b * 128 + f;
        float rw = revin_w[f], rb = revin_b[f];
        float sc = rw * rcpf(sd);
        sc_o[r] = sc;
        sh_o[r] = rb - m * sc;
        float oc = sd * rcpf(rw);
        osc_o[r] = oc;
        osh_o[r] = m - rb * oc;
    }
}

// ---------------- K2: u = xn_seg @ W_enc + b_enc  (fp32 GEMM, out bf16) ----------------
// block = (b, n); A: 24x128 (f), B: 24x128 (d); out u[(b*128+f)*14+n][d]
__global__ __launch_bounds__(256) void k_u(
    const float* __restrict__ x, const float* __restrict__ sc_i, const float* __restrict__ sh_i,
    const float* __restrict__ W_enc, const float* __restrict__ b_enc,
    ushort* __restrict__ ub) {
    __shared__ float xs[24][132];
    __shared__ float ws[24][192];   // 8-float chunks at stride 12 (2-way banks, free)
    int bid = blockIdx.x;
    int b = bid / 14, n = bid - b * 14;
    int tid = threadIdx.x;
    for (int e = tid; e < 24 * 128; e += 256) {
        int s = e >> 7, f = e & 127;
        xs[s][f] = x[((size_t)b * 336 + n * 24 + s) * 128 + f] * sc_i[b * 128 + f] + sh_i[b * 128 + f];
        ws[s][(f >> 3) * 12 + (f & 7)] = W_enc[s * 128 + f];
    }
    __syncthreads();
    int dchunk = tid & 15, fg = tid >> 4;
    int d0 = dchunk * 8, f0 = fg * 8;
    float acc[8][8];
#pragma unroll
    for (int i = 0; i < 8; ++i)
#pragma unroll
        for (int j = 0; j < 8; ++j) acc[i][j] = 0.f;
#pragma unroll
    for (int s = 0; s < 24; ++s) {
        f32x4 xa = *(const f32x4*)&xs[s][f0];
        f32x4 xb2 = *(const f32x4*)&xs[s][f0 + 4];
        f32x4 wa = *(const f32x4*)&ws[s][dchunk * 12];
        f32x4 wb = *(const f32x4*)&ws[s][dchunk * 12 + 4];
        float xv[8], wv[8];
#pragma unroll
        for (int q = 0; q < 4; ++q) { xv[q] = xa[q]; xv[q + 4] = xb2[q]; wv[q] = wa[q]; wv[q + 4] = wb[q]; }
#pragma unroll
        for (int i = 0; i < 8; ++i)
#pragma unroll
            for (int j = 0; j < 8; ++j) acc[i][j] += xv[i] * wv[j];
    }
    float bj[8];
#pragma unroll
    for (int j = 0; j < 8; ++j) bj[j] = b_enc[d0 + j];
#pragma unroll
    for (int i = 0; i < 8; ++i) {
        ushort8v o;
#pragma unroll
        for (int j = 0; j < 8; ++j) o[j] = f2bf(acc[i][j] + bj[j]);
        *(ushort8v*)&ub[(((size_t)(b * 128 + f0 + i)) * 14 + n) * 128 + d0] = o;
    }
}

// ---------------- K3: hyperbolic recurrence (wave-per-row), scalarized ----------------
__global__ __launch_bounds__(256) void k_encode(
    const ushort* __restrict__ ub,
    float* __restrict__ z0_o, float* __restrict__ vinit_o) {
    int wid = threadIdx.x >> 6, lane = threadIdx.x & 63;
    int r = blockIdx.x * 4 + wid;
    const ushort* up_ptr = ub + (size_t)r * 14 * 128;
    float uv0[14], uv1[14];
#pragma unroll
    for (int n = 0; n < 14; ++n) {
        uv0[n] = bf2f(up_ptr[n * 128 + lane]);
        uv1[n] = bf2f(up_ptr[n * 128 + lane + 64]);
    }
    float wsum = 0.f;
    { float p = 1.f; for (int k = 0; k < 13; ++k) { wsum += p; p *= 0.9f; } }
    float wi; { float p = 1.f; for (int k = 0; k < 12; ++k) p *= 0.9f; wi = p / (wsum * 13.f); }

    float up0 = 0.f, up1 = 0.f, sczp = 0.f, szp = 0.f, vac0 = 0.f, vac1 = 0.f;
#pragma unroll
    for (int n = 0; n < 14; ++n) {
        float u0 = uv0[n], u1 = uv1[n];
        float ssq = wave_sum(u0 * u0 + u1 * u1);
        float nn = sqrtf(fmaxf(ssq, EPSF));
        float th = tanh_g(nn);
        float scz, sz;
        if (th > MAXNF) { scz = MAXNF * rcpf(nn); sz = MAXNF * MAXNF; }
        else            { scz = th * rcpf(nn);    sz = th * th; }
        if (n > 0) {
            float dotup = wave_sum(up0 * u0 + up1 * u1);
            float xyp = sczp * scz * dotup;            // sum zp.z
            float t2 = 1.f - 2.f * xyp;                // 1 + 2xy, xy = -xyp
            float den = fmaxf(t2 + szp * sz, EPSF);
            float rden = rcpf(den);
            float a1 = t2 + sz, a2 = 1.f - szp;
            float usq = (a1 * a1 * szp - 2.f * a1 * a2 * xyp + a2 * a2 * sz) * (rden * rden);
            float un = sqrtf(fmaxf(usq, EPSF));
            float art = atanh_g(fminf(un, 1.f - 1e-7f));
            float fac = fmaxf(a2, EPSF) * art * rcpf(un) * rden * wi;
            float p = -fac * a1 * sczp;
            float q = fac * a2 * scz;
            vac0 += p * up0 + q * u0;
            vac1 += p * up1 + q * u1;
            wi *= (1.f / 0.9f);
        }
        up0 = u0; up1 = u1; sczp = scz; szp = sz;
    }
    size_t base = (size_t)r * 128;
    z0_o[base + lane] = sczp * up0;
    z0_o[base + lane + 64] = sczp * up1;
    vinit_o[base + lane] = vac0;
    vinit_o[base + lane + 64] = vac1;
}

// ---------------- K4: mx = v_init @ W_vel^T  (8 rows/block, 4 rows/thread) ----------------
__global__ __launch_bounds__(256) void k_matvec(
    const float* __restrict__ vinit, const float* __restrict__ W_vel,
    float* __restrict__ mx_o) {
    __shared__ float vv[8][128];
    int tid = threadIdx.x;
    int r0 = blockIdx.x * 8;
    for (int i = tid; i < 1024; i += 256) vv[i >> 7][i & 127] = vinit[(size_t)r0 * 128 + i];
    __syncthreads();
    int d = tid & 127, h = tid >> 7;
    float m0 = 0.f, m1 = 0.f, m2 = 0.f, m3 = 0.f;
    const float4* wr = reinterpret_cast<const float4*>(W_vel + (size_t)d * 128);
    const float4* v0 = reinterpret_cast<const float4*>(vv[h * 4 + 0]);
    const float4* v1 = reinterpret_cast<const float4*>(vv[h * 4 + 1]);
    const float4* v2 = reinterpret_cast<const float4*>(vv[h * 4 + 2]);
    const float4* v3 = reinterpret_cast<const float4*>(vv[h * 4 + 3]);
#pragma unroll 8
    for (int j = 0; j < 32; ++j) {
        float4 w = wr[j];
        float4 a = v0[j]; m0 += w.x * a.x + w.y * a.y + w.z * a.z + w.w * a.w;
        float4 bb = v1[j]; m1 += w.x * bb.x + w.y * bb.y + w.z * bb.z + w.w * bb.w;
        float4 c = v2[j]; m2 += w.x * c.x + w.y * c.y + w.z * c.z + w.w * c.w;
        float4 e = v3[j]; m3 += w.x * e.x + w.y * e.y + w.z * e.z + w.w * e.w;
    }
    mx_o[(size_t)(r0 + h * 4 + 0) * 128 + d] = m0;
    mx_o[(size_t)(r0 + h * 4 + 1) * 128 + d] = m1;
    mx_o[(size_t)(r0 + h * 4 + 2) * 128 + d] = m2;
    mx_o[(size_t)(r0 + h * 4 + 3) * 128 + d] = m3;
}

// ---------------- K5: v0t tail + futures -> tan (bf16); t-loop fully scalar ----------------
__global__ __launch_bounds__(256) void k_future(
    const float* __restrict__ z0_i, const float* __restrict__ vinit, const float* __restrict__ mx_i,
    const float* __restrict__ cvec, const float* __restrict__ scp,
    const float* __restrict__ step_sizes, ushort* __restrict__ tanb) {
    int wid = threadIdx.x >> 6, lane = threadIdx.x & 63;
    int r = blockIdx.x * 4 + wid;
    size_t base = (size_t)r * 128;
    float vi0 = vinit[base + lane], vi1 = vinit[base + lane + 64];
    float mx0 = mx_i[base + lane], mx1 = mx_i[base + lane + 64];
    float z00 = z0_i[base + lane], z01 = z0_i[base + lane + 64];
    float c0 = cvec[lane], c1 = cvec[lane + 64];
    float scc = scp[0];
    float xn2  = wave_sum(vi0 * vi0 + vi1 * vi1);
    float mxn2 = wave_sum(mx0 * mx0 + mx1 * mx1);
    float mxc  = wave_sum(mx0 * c0 + mx1 * c1);
    float z0mx = wave_sum(z00 * mx0 + z01 * mx1);
    float z0c  = wave_sum(z00 * c0 + z01 * c1);
    float x2   = wave_sum(z00 * z00 + z01 * z01);
    // mobius_matvec tail: m = scm * mx
    float xn = sqrtf(fmaxf(xn2, EPSF));
    float mxn = sqrtf(fmaxf(mxn2, EPSF));
    float artx = atanh_g(fminf(xn, 1.f - 1e-7f));
    float tm = tanh_g(mxn * rcpf(xn) * artx);
    float scm = tm * rcpf(mxn);
    float sm = tm * tm;
    // mobius_add(m, c) -> v0 = A2*mx + B2*c, then projx
    float xy2 = scm * mxc;
    float den2 = fmaxf(1.f + 2.f * xy2 + sm * scc, EPSF);
    float rd2 = rcpf(den2);
    float A2 = (1.f + 2.f * xy2 + scc) * scm * rd2;
    float B2 = (1.f - sm) * rd2;
    float v0n2 = A2 * A2 * mxn2 + 2.f * A2 * B2 * mxc + B2 * B2 * scc;
    float nv0 = sqrtf(fmaxf(v0n2, EPSF));
    if (nv0 > MAXNF) { float pf = MAXNF * rcpf(nv0); A2 *= pf; B2 *= pf; nv0 = MAXNF; }
    v0n2 = nv0 * nv0;
    float inv_nv0 = rcpf(nv0);
    float zdv = A2 * z0mx + B2 * z0c;            // sum z0.v0
    float v00 = A2 * mx0 + B2 * c0, v01 = A2 * mx1 + B2 * c1;
    float il = rcpf(fmaxf(1.f - x2, EPSF));      // lam/2
    float step = rcpf(1.f + __expf(-step_sizes[0]));
#pragma unroll
    for (int t = 1; t <= 8; ++t) {
        float nt = step * (float)t * nv0;
        float th = tanh_g(nt * il);
        float xy = th * inv_nv0 * zdv;
        float y2 = th * th;
        float den = fmaxf(1.f + 2.f * xy + x2 * y2, EPSF);
        float rd = rcpf(den);
        float A = (1.f + 2.f * xy + y2) * rd;
        float B = (1.f - x2) * th * inv_nv0 * rd;
        float rsq = A * A * x2 + 2.f * A * B * zdv + B * B * v0n2;
        float nr = sqrtf(fmaxf(rsq, EPSF));
        if (nr > MAXNF) { float pf = MAXNF * rcpf(nr); A *= pf; B *= pf; nr = MAXNF; }
        float art = atanh_g(fminf(nr, 1.f - 1e-7f));
        float tf = art * rcpf(nr);
        float FA = tf * A, FB = tf * B;
        size_t ob = ((size_t)r * 8 + (t - 1)) * 128;
        tanb[ob + lane] = f2bf(FA * z00 + FB * v00);
        tanb[ob + lane + 64] = f2bf(FA * z01 + FB * v01);
    }
}

// ---------------- K6: head via bf16 MFMA (64 rows/block, 16 rows/wave) ----------------
__global__ __launch_bounds__(256) void k_head(
    const ushort* __restrict__ tanb, const ushort* __restrict__ W1t, const float* __restrict__ b1,
    const ushort* __restrict__ W2tp, const float* __restrict__ b2,
    const float* __restrict__ osc_i, const float* __restrict__ osh_i,
    float* __restrict__ out) {
    __shared__ __align__(16) ushort hs[4][16][264];
    int wid = threadIdx.x >> 6, lane = threadIdx.x & 63;
    int r0 = blockIdx.x * 64 + wid * 16;
    int lrow = lane & 15, lk = lane >> 4;
    short8v A[4];
    const ushort* tp = tanb + (size_t)(r0 + lrow) * 128 + lk * 8;
#pragma unroll
    for (int kk = 0; kk < 4; ++kk) A[kk] = *reinterpret_cast<const short8v*>(tp + kk * 32);
    f32x4 acc[16];
#pragma unroll
    for (int nt = 0; nt < 16; ++nt) acc[nt] = (f32x4)(0.f);
#pragma unroll
    for (int nt = 0; nt < 16; ++nt) {
        const ushort* wp = W1t + (size_t)(nt * 16 + lrow) * 128 + lk * 8;
#pragma unroll
        for (int kk = 0; kk < 4; ++kk) {
            short8v B = *reinterpret_cast<const short8v*>(wp + kk * 32);
            acc[nt] = __builtin_amdgcn_mfma_f32_16x16x32_bf16(A[kk], B, acc[nt], 0, 0, 0);
        }
    }
#pragma unroll
    for (int nt = 0; nt < 16; ++nt) {
        float bv = b1[nt * 16 + lrow];
#pragma unroll
        for (int j = 0; j < 4; ++j) {
            float h = fmaxf(acc[nt][j] + bv, 0.f);
            hs[wid][lk * 4 + j][nt * 16 + lrow] = f2bf(h);
        }
    }
    __syncthreads();
    f32x4 acc2[2];
    acc2[0] = (f32x4)(0.f); acc2[1] = (f32x4)(0.f);
#pragma unroll
    for (int kk = 0; kk < 8; ++kk) {
        short8v Ah = *reinterpret_cast<const short8v*>(&hs[wid][lrow][kk * 32 + lk * 8]);
#pragma unroll
        for (int nt = 0; nt < 2; ++nt) {
            short8v B = *reinterpret_cast<const short8v*>(W2tp + (size_t)(nt * 16 + lrow) * 256 + kk * 32 + lk * 8);
            acc2[nt] = __builtin_amdgcn_mfma_f32_16x16x32_bf16(Ah, B, acc2[nt], 0, 0, 0);
        }
    }
#pragma unroll
    for (int nt = 0; nt < 2; ++nt) {
        int col = nt * 16 + lrow;
        if (col < 24) {
            float b2v = b2[col];
#pragma unroll
            for (int j = 0; j < 4; ++j) {
                int row = r0 + lk * 4 + j;
                int rI = row >> 3, tt = row & 7;
                int bb = rI >> 7, f = rI & 127;
                float v = acc2[nt][j] + b2v;
                v = v * osc_i[rI] + osh_i[rI];
                out[((size_t)bb * 192 + tt * 24 + col) * 128 + f] = v;
            }
        }
    }
}

extern "C" void kernel_launch(void* const* d_in, const int* in_sizes, int n_in,
                              void* d_out, int out_size, void* d_ws, size_t ws_size,
                              hipStream_t stream) {
    (void)in_sizes; (void)n_in; (void)out_size; (void)ws_size;
    const float* x          = (const float*)d_in[0];
    const float* revin_w    = (const float*)d_in[1];
    const float* revin_b    = (const float*)d_in[2];
    const float* W_enc      = (const float*)d_in[3];
    const float* b_enc      = (const float*)d_in[4];
    const float* W_vel      = (const float*)d_in[5];
    const float* b_vel      = (const float*)d_in[6];
    const float* step_sizes = (const float*)d_in[7];
    const float* W1         = (const float*)d_in[8];
    const float* b1         = (const float*)d_in[9];
    const float* W2         = (const float*)d_in[10];
    const float* b2         = (const float*)d_in[11];
    float* out = (float*)d_out;

    float* wsf   = (float*)d_ws;
    float* sc    = wsf;                          // 16384
    float* sh    = sc + 16384;
    float* osc   = sh + 16384;
    float* osh   = osc + 16384;
    float* z0    = osh + 16384;                  // 16384*128
    float* vinit = z0 + (size_t)16384 * 128;
    float* mx    = vinit + (size_t)16384 * 128;
    float* cvec  = mx + (size_t)16384 * 128;     // 128
    float* scp   = cvec + 128;                   // 64 (pad)
    ushort* W1t  = (ushort*)(scp + 64);          // 32768
    ushort* W2tp = W1t + 32768;                  // 8192
    ushort* ub   = W2tp + 8192;                  // 229376*128 bf16 (58.7MB)
    ushort* tanb = ub;                           // aliased: ub dead before k_future writes

    k_prep<<<dim3(161), dim3(256), 0, stream>>>(W1, W2, b_vel, W1t, W2tp, cvec, scp);
    k_stats<<<dim3(128), dim3(1024), 0, stream>>>(x, revin_w, revin_b, sc, sh, osc, osh);
    k_u<<<dim3(1792), dim3(256), 0, stream>>>(x, sc, sh, W_enc, b_enc, ub);
    k_encode<<<dim3(4096), dim3(256), 0, stream>>>(ub, z0, vinit);
    k_matvec<<<dim3(2048), dim3(256), 0, stream>>>(vinit, W_vel, mx);
    k_future<<<dim3(4096), dim3(256), 0, stream>>>(z0, vinit, mx, cvec, scp, step_sizes, tanb);
    k_head<<<dim3(2048), dim3(256), 0, stream>>>(tanb, W1t, b1, W2tp, b2, osc, osh, out);
}

// Round 4
// 193.158 us; speedup vs baseline: 3.6773x; 1.2316x over previous
//
#include <hip/hip_runtime.h>
#include <hip/hip_bf16.h>

#define EPSF 1e-15f
#define MAXNF 0.99999f

typedef __attribute__((ext_vector_type(8))) short short8v;
typedef __attribute__((ext_vector_type(8))) ushort ushort8v;
typedef __attribute__((ext_vector_type(4))) float f32x4;

__device__ __forceinline__ float wave_sum(float v) {
#pragma unroll
    for (int off = 32; off > 0; off >>= 1) v += __shfl_xor(v, off, 64);
    return v;
}
__device__ __forceinline__ float rcpf(float x) { return __builtin_amdgcn_rcpf(x); }
// x >= 0; series guard avoids (1-e) cancellation at small x
__device__ __forceinline__ float tanh_g(float x) {
    if (x < 0.03f) return x * (1.f - 0.33333333f * x * x);
    float e = __expf(-2.f * x);
    return (1.f - e) * rcpf(1.f + e);
}
// 0 <= x <= 1-1e-7
__device__ __forceinline__ float atanh_g(float x) {
    if (x < 0.03f) return x * (1.f + 0.33333333f * x * x);
    return 0.5f * __logf((1.f + x) * rcpf(1.f - x));
}
__device__ __forceinline__ ushort f2bf(float f) {
    uint32_t u = __float_as_uint(f);
    uint32_t r = (u + 0x7fffu + ((u >> 16) & 1u)) >> 16;
    return (ushort)r;
}
__device__ __forceinline__ float bf2f(ushort u) { return __uint_as_float(((uint32_t)u) << 16); }

// ---------------- K0: prep — W1^T/W2^T to bf16, c = expmap0(b_vel) ----------------
__global__ __launch_bounds__(256) void k_prep(
    const float* __restrict__ W1, const float* __restrict__ W2,
    const float* __restrict__ b_vel,
    ushort* __restrict__ W1t, ushort* __restrict__ W2tp,
    float* __restrict__ cvec, float* __restrict__ scp) {
    int bid = blockIdx.x, tid = threadIdx.x;
    if (bid == 0) {
        __shared__ float red[4];
        float v = (tid < 128) ? b_vel[tid] : 0.f;
        float p = wave_sum(v * v);
        if ((tid & 63) == 0) red[tid >> 6] = p;
        __syncthreads();
        float ssq = red[0] + red[1] + red[2] + red[3];
        float nn = sqrtf(fmaxf(ssq, EPSF));
        float th = tanhf(nn);
        if (tid < 128) cvec[tid] = th / nn * v;
        if (tid == 0) scp[0] = th * th;
    } else if (bid <= 128) {
        int idx = (bid - 1) * 256 + tid;      // n*128 + k
        int n = idx >> 7, k = idx & 127;
        W1t[idx] = f2bf(W1[k * 256 + n]);
    } else {
        int idx = (bid - 129) * 256 + tid;    // s*256 + j  (s padded to 32)
        int s = idx >> 8, j = idx & 255;
        W2tp[idx] = (s < 24) ? f2bf(W2[j * 24 + s]) : (ushort)0;
    }
}

// ---------------- K1: RevIN stats -> norm coeffs (sc,sh) + denorm coeffs (osc,osh) ----------------
__global__ __launch_bounds__(1024) void k_stats(
    const float* __restrict__ x, const float* __restrict__ revin_w, const float* __restrict__ revin_b,
    float* __restrict__ sc_o, float* __restrict__ sh_o,
    float* __restrict__ osc_o, float* __restrict__ osh_o) {
    __shared__ float ps[8][128], ps2[8][128];
    int b = blockIdx.x, tid = threadIdx.x;
    int f = tid & 127, half = tid >> 7;   // 8 L-slices of 42
    const float* xp = x + ((size_t)b * 336 + half * 42) * 128 + f;
    float s = 0.f, s2 = 0.f;
    for (int l = 0; l < 42; ++l) { float v = xp[(size_t)l * 128]; s += v; s2 += v * v; }
    ps[half][f] = s; ps2[half][f] = s2;
    __syncthreads();
    if (tid < 128) {
        float S = 0.f, S2 = 0.f;
#pragma unroll
        for (int h = 0; h < 8; ++h) { S += ps[h][f]; S2 += ps2[h][f]; }
        float m = S * (1.f / 336.f);
        float var = S2 * (1.f / 336.f) - m * m;
        float sd = sqrtf(var + 1e-5f);
        int r = b * 128 + f;
        float rw = revin_w[f], rb = revin_b[f];
        float sc = rw * rcpf(sd);
        sc_o[r] = sc;
        sh_o[r] = rb - m * sc;
        float oc = sd * rcpf(rw);
        osc_o[r] = oc;
        osh_o[r] = m - rb * oc;
    }
}

// ---------------- K2: u = xn_seg @ W_enc + b_enc  (fp32 GEMM, out bf16) ----------------
__global__ __launch_bounds__(256) void k_u(
    const float* __restrict__ x, const float* __restrict__ sc_i, const float* __restrict__ sh_i,
    const float* __restrict__ W_enc, const float* __restrict__ b_enc,
    ushort* __restrict__ ub) {
    __shared__ float xs[24][132];
    __shared__ float ws[24][192];   // 8-float chunks at stride 12 (2-way banks, free)
    int bid = blockIdx.x;
    int b = bid / 14, n = bid - b * 14;
    int tid = threadIdx.x;
    for (int e = tid; e < 24 * 128; e += 256) {
        int s = e >> 7, f = e & 127;
        xs[s][f] = x[((size_t)b * 336 + n * 24 + s) * 128 + f] * sc_i[b * 128 + f] + sh_i[b * 128 + f];
        ws[s][(f >> 3) * 12 + (f & 7)] = W_enc[s * 128 + f];
    }
    __syncthreads();
    int dchunk = tid & 15, fg = tid >> 4;
    int d0 = dchunk * 8, f0 = fg * 8;
    float acc[8][8];
#pragma unroll
    for (int i = 0; i < 8; ++i)
#pragma unroll
        for (int j = 0; j < 8; ++j) acc[i][j] = 0.f;
#pragma unroll
    for (int s = 0; s < 24; ++s) {
        f32x4 xa = *(const f32x4*)&xs[s][f0];
        f32x4 xb2 = *(const f32x4*)&xs[s][f0 + 4];
        f32x4 wa = *(const f32x4*)&ws[s][dchunk * 12];
        f32x4 wb = *(const f32x4*)&ws[s][dchunk * 12 + 4];
        float xv[8], wv[8];
#pragma unroll
        for (int q = 0; q < 4; ++q) { xv[q] = xa[q]; xv[q + 4] = xb2[q]; wv[q] = wa[q]; wv[q + 4] = wb[q]; }
#pragma unroll
        for (int i = 0; i < 8; ++i)
#pragma unroll
            for (int j = 0; j < 8; ++j) acc[i][j] += xv[i] * wv[j];
    }
    float bj[8];
#pragma unroll
    for (int j = 0; j < 8; ++j) bj[j] = b_enc[d0 + j];
#pragma unroll
    for (int i = 0; i < 8; ++i) {
        ushort8v o;
#pragma unroll
        for (int j = 0; j < 8; ++j) o[j] = f2bf(acc[i][j] + bj[j]);
        *(ushort8v*)&ub[(((size_t)(b * 128 + f0 + i)) * 14 + n) * 128 + d0] = o;
    }
}

// ---------------- K3: hyperbolic recurrence (wave-per-row), scalarized ----------------
__global__ __launch_bounds__(256) void k_encode(
    const ushort* __restrict__ ub,
    float* __restrict__ z0_o, float* __restrict__ vinit_o) {
    int wid = threadIdx.x >> 6, lane = threadIdx.x & 63;
    int r = blockIdx.x * 4 + wid;
    const ushort* up_ptr = ub + (size_t)r * 14 * 128;
    float uv0[14], uv1[14];
#pragma unroll
    for (int n = 0; n < 14; ++n) {
        uv0[n] = bf2f(up_ptr[n * 128 + lane]);
        uv1[n] = bf2f(up_ptr[n * 128 + lane + 64]);
    }
    float wsum = 0.f;
    { float p = 1.f; for (int k = 0; k < 13; ++k) { wsum += p; p *= 0.9f; } }
    float wi; { float p = 1.f; for (int k = 0; k < 12; ++k) p *= 0.9f; wi = p / (wsum * 13.f); }

    float up0 = 0.f, up1 = 0.f, sczp = 0.f, szp = 0.f, vac0 = 0.f, vac1 = 0.f;
#pragma unroll
    for (int n = 0; n < 14; ++n) {
        float u0 = uv0[n], u1 = uv1[n];
        float ssq = wave_sum(u0 * u0 + u1 * u1);
        float nn = sqrtf(fmaxf(ssq, EPSF));
        float th = tanh_g(nn);
        float scz, sz;
        if (th > MAXNF) { scz = MAXNF * rcpf(nn); sz = MAXNF * MAXNF; }
        else            { scz = th * rcpf(nn);    sz = th * th; }
        if (n > 0) {
            float dotup = wave_sum(up0 * u0 + up1 * u1);
            float xyp = sczp * scz * dotup;            // sum zp.z
            float t2 = 1.f - 2.f * xyp;                // 1 + 2xy, xy = -xyp
            float den = fmaxf(t2 + szp * sz, EPSF);
            float rden = rcpf(den);
            float a1 = t2 + sz, a2 = 1.f - szp;
            float usq = (a1 * a1 * szp - 2.f * a1 * a2 * xyp + a2 * a2 * sz) * (rden * rden);
            float un = sqrtf(fmaxf(usq, EPSF));
            float art = atanh_g(fminf(un, 1.f - 1e-7f));
            float fac = fmaxf(a2, EPSF) * art * rcpf(un) * rden * wi;
            float p = -fac * a1 * sczp;
            float q = fac * a2 * scz;
            vac0 += p * up0 + q * u0;
            vac1 += p * up1 + q * u1;
            wi *= (1.f / 0.9f);
        }
        up0 = u0; up1 = u1; sczp = scz; szp = sz;
    }
    size_t base = (size_t)r * 128;
    z0_o[base + lane] = sczp * up0;
    z0_o[base + lane + 64] = sczp * up1;
    vinit_o[base + lane] = vac0;
    vinit_o[base + lane + 64] = vac1;
}

// ---------------- K4: mx = v_init @ W_vel^T  (8 rows/block, 4 rows/thread) ----------------
__global__ __launch_bounds__(256) void k_matvec(
    const float* __restrict__ vinit, const float* __restrict__ W_vel,
    float* __restrict__ mx_o) {
    __shared__ float vv[8][128];
    int tid = threadIdx.x;
    int r0 = blockIdx.x * 8;
    for (int i = tid; i < 1024; i += 256) vv[i >> 7][i & 127] = vinit[(size_t)r0 * 128 + i];
    __syncthreads();
    int d = tid & 127, h = tid >> 7;
    float m0 = 0.f, m1 = 0.f, m2 = 0.f, m3 = 0.f;
    const float4* wr = reinterpret_cast<const float4*>(W_vel + (size_t)d * 128);
    const float4* v0 = reinterpret_cast<const float4*>(vv[h * 4 + 0]);
    const float4* v1 = reinterpret_cast<const float4*>(vv[h * 4 + 1]);
    const float4* v2 = reinterpret_cast<const float4*>(vv[h * 4 + 2]);
    const float4* v3 = reinterpret_cast<const float4*>(vv[h * 4 + 3]);
#pragma unroll 8
    for (int j = 0; j < 32; ++j) {
        float4 w = wr[j];
        float4 a = v0[j]; m0 += w.x * a.x + w.y * a.y + w.z * a.z + w.w * a.w;
        float4 bb = v1[j]; m1 += w.x * bb.x + w.y * bb.y + w.z * bb.z + w.w * bb.w;
        float4 c = v2[j]; m2 += w.x * c.x + w.y * c.y + w.z * c.z + w.w * c.w;
        float4 e = v3[j]; m3 += w.x * e.x + w.y * e.y + w.z * e.z + w.w * e.w;
    }
    mx_o[(size_t)(r0 + h * 4 + 0) * 128 + d] = m0;
    mx_o[(size_t)(r0 + h * 4 + 1) * 128 + d] = m1;
    mx_o[(size_t)(r0 + h * 4 + 2) * 128 + d] = m2;
    mx_o[(size_t)(r0 + h * 4 + 3) * 128 + d] = m3;
}

// ---------------- K5: v0t tail + futures -> tan (bf16); t-loop fully scalar ----------------
__global__ __launch_bounds__(256) void k_future(
    const float* __restrict__ z0_i, const float* __restrict__ vinit, const float* __restrict__ mx_i,
    const float* __restrict__ cvec, const float* __restrict__ scp,
    const float* __restrict__ step_sizes, ushort* __restrict__ tanb) {
    int wid = threadIdx.x >> 6, lane = threadIdx.x & 63;
    int r = blockIdx.x * 4 + wid;
    size_t base = (size_t)r * 128;
    float vi0 = vinit[base + lane], vi1 = vinit[base + lane + 64];
    float mx0 = mx_i[base + lane], mx1 = mx_i[base + lane + 64];
    float z00 = z0_i[base + lane], z01 = z0_i[base + lane + 64];
    float c0 = cvec[lane], c1 = cvec[lane + 64];
    float scc = scp[0];
    float xn2  = wave_sum(vi0 * vi0 + vi1 * vi1);
    float mxn2 = wave_sum(mx0 * mx0 + mx1 * mx1);
    float mxc  = wave_sum(mx0 * c0 + mx1 * c1);
    float z0mx = wave_sum(z00 * mx0 + z01 * mx1);
    float z0c  = wave_sum(z00 * c0 + z01 * c1);
    float x2   = wave_sum(z00 * z00 + z01 * z01);
    // mobius_matvec tail: m = scm * mx
    float xn = sqrtf(fmaxf(xn2, EPSF));
    float mxn = sqrtf(fmaxf(mxn2, EPSF));
    float artx = atanh_g(fminf(xn, 1.f - 1e-7f));
    float tm = tanh_g(mxn * rcpf(xn) * artx);
    float scm = tm * rcpf(mxn);
    float sm = tm * tm;
    // mobius_add(m, c) -> v0 = A2*mx + B2*c, then projx
    float xy2 = scm * mxc;
    float den2 = fmaxf(1.f + 2.f * xy2 + sm * scc, EPSF);
    float rd2 = rcpf(den2);
    float A2 = (1.f + 2.f * xy2 + scc) * scm * rd2;
    float B2 = (1.f - sm) * rd2;
    float v0n2 = A2 * A2 * mxn2 + 2.f * A2 * B2 * mxc + B2 * B2 * scc;
    float nv0 = sqrtf(fmaxf(v0n2, EPSF));
    if (nv0 > MAXNF) { float pf = MAXNF * rcpf(nv0); A2 *= pf; B2 *= pf; nv0 = MAXNF; }
    v0n2 = nv0 * nv0;
    float inv_nv0 = rcpf(nv0);
    float zdv = A2 * z0mx + B2 * z0c;            // sum z0.v0
    float v00 = A2 * mx0 + B2 * c0, v01 = A2 * mx1 + B2 * c1;
    float il = rcpf(fmaxf(1.f - x2, EPSF));      // lam/2
    float step = rcpf(1.f + __expf(-step_sizes[0]));
#pragma unroll
    for (int t = 1; t <= 8; ++t) {
        float nt = step * (float)t * nv0;
        float th = tanh_g(nt * il);
        float xy = th * inv_nv0 * zdv;
        float y2 = th * th;
        float den = fmaxf(1.f + 2.f * xy + x2 * y2, EPSF);
        float rd = rcpf(den);
        float A = (1.f + 2.f * xy + y2) * rd;
        float B = (1.f - x2) * th * inv_nv0 * rd;
        float rsq = A * A * x2 + 2.f * A * B * zdv + B * B * v0n2;
        float nr = sqrtf(fmaxf(rsq, EPSF));
        if (nr > MAXNF) { float pf = MAXNF * rcpf(nr); A *= pf; B *= pf; nr = MAXNF; }
        float art = atanh_g(fminf(nr, 1.f - 1e-7f));
        float tf = art * rcpf(nr);
        float FA = tf * A, FB = tf * B;
        size_t ob = ((size_t)r * 8 + (t - 1)) * 128;
        tanb[ob + lane] = f2bf(FA * z00 + FB * v00);
        tanb[ob + lane + 64] = f2bf(FA * z01 + FB * v01);
    }
}

// ---------------- K6: head — N-split waves, B-resident, 2-tile loop ----------------
// grid 1024 x 256. Each block: 2 tiles of 64 rows. Wave w owns GEMM1 cols [w*64,w*64+64).
__global__ __launch_bounds__(256, 2) void k_head(
    const ushort* __restrict__ tanb, const ushort* __restrict__ W1t, const float* __restrict__ b1,
    const ushort* __restrict__ W2tp, const float* __restrict__ b2,
    const float* __restrict__ osc_i, const float* __restrict__ osh_i,
    float* __restrict__ out) {
    __shared__ __align__(16) ushort hs[64][264];
    int wid = threadIdx.x >> 6, lane = threadIdx.x & 63;
    int lrow = lane & 15, lk = lane >> 4;

    // persistent GEMM1 B-frags: this wave's 64 N-cols (loaded once)
    short8v Bw[4][4];
#pragma unroll
    for (int nt = 0; nt < 4; ++nt) {
        const ushort* wp = W1t + (size_t)((wid * 4 + nt) * 16 + lrow) * 128 + lk * 8;
#pragma unroll
        for (int kk = 0; kk < 4; ++kk) Bw[nt][kk] = *(const short8v*)(wp + kk * 32);
    }
    float b1v[4];
#pragma unroll
    for (int nt = 0; nt < 4; ++nt) b1v[nt] = b1[(wid * 4 + nt) * 16 + lrow];
    float b2a = (lrow < 24) ? b2[lrow] : 0.f;          // nt2=0 cols
    float b2bv = (lrow < 8) ? b2[16 + lrow] : 0.f;     // nt2=1 cols

    int tile0 = blockIdx.x * 2;
    // preload A for tile 0 (64 rows: 4 row-groups x 4 k-chunks)
    short8v A[4][4];
    {
        const ushort* tp = tanb + ((size_t)tile0 * 64 + lrow) * 128 + lk * 8;
#pragma unroll
        for (int rg = 0; rg < 4; ++rg)
#pragma unroll
            for (int kk = 0; kk < 4; ++kk)
                A[rg][kk] = *(const short8v*)(tp + (size_t)rg * 2048 + kk * 32);
    }
#pragma unroll
    for (int it = 0; it < 2; ++it) {
        int r0 = (tile0 + it) * 64;
        f32x4 acc[4][4];
#pragma unroll
        for (int rg = 0; rg < 4; ++rg)
#pragma unroll
            for (int nt = 0; nt < 4; ++nt) acc[rg][nt] = (f32x4)(0.f);
#pragma unroll
        for (int kk = 0; kk < 4; ++kk)
#pragma unroll
            for (int rg = 0; rg < 4; ++rg)
#pragma unroll
                for (int nt = 0; nt < 4; ++nt)
                    acc[rg][nt] = __builtin_amdgcn_mfma_f32_16x16x32_bf16(A[rg][kk], Bw[nt][kk], acc[rg][nt], 0, 0, 0);
        // prefetch next tile's A; latency hides under LDS + GEMM2 + epilogue
        if (it + 1 < 2) {
            const ushort* tp = tanb + ((size_t)(tile0 + it + 1) * 64 + lrow) * 128 + lk * 8;
#pragma unroll
            for (int rg = 0; rg < 4; ++rg)
#pragma unroll
                for (int kk = 0; kk < 4; ++kk)
                    A[rg][kk] = *(const short8v*)(tp + (size_t)rg * 2048 + kk * 32);
        }
        __syncthreads();   // protect previous iter's hs reads before overwrite (no-op on it 0)
        // h slice -> LDS: rows rg*16+lk*4+j, col (wid*4+nt)*16+lrow
#pragma unroll
        for (int rg = 0; rg < 4; ++rg)
#pragma unroll
            for (int nt = 0; nt < 4; ++nt)
#pragma unroll
                for (int j = 0; j < 4; ++j)
                    hs[rg * 16 + lk * 4 + j][(wid * 4 + nt) * 16 + lrow] =
                        f2bf(fmaxf(acc[rg][nt][j] + b1v[nt], 0.f));
        __syncthreads();
        // GEMM2: wave computes its 16 rows over full K=256
        f32x4 acc2[2];
        acc2[0] = (f32x4)(0.f); acc2[1] = (f32x4)(0.f);
#pragma unroll
        for (int kk2 = 0; kk2 < 8; ++kk2) {
            short8v Ah = *(const short8v*)&hs[wid * 16 + lrow][kk2 * 32 + lk * 8];
#pragma unroll
            for (int nt2 = 0; nt2 < 2; ++nt2) {
                short8v Bv = *(const short8v*)(W2tp + (size_t)(nt2 * 16 + lrow) * 256 + kk2 * 32 + lk * 8);
                acc2[nt2] = __builtin_amdgcn_mfma_f32_16x16x32_bf16(Ah, Bv, acc2[nt2], 0, 0, 0);
            }
        }
        // epilogue: +b2, denorm, transposed scatter store
#pragma unroll
        for (int nt2 = 0; nt2 < 2; ++nt2) {
            int col = nt2 * 16 + lrow;
            if (col < 24) {
                float bb2 = (nt2 == 0) ? b2a : b2bv;
#pragma unroll
                for (int j = 0; j < 4; ++j) {
                    int row = r0 + wid * 16 + lk * 4 + j;
                    int rI = row >> 3, tt = row & 7;
                    int bb = rI >> 7, f = rI & 127;
                    float v = acc2[nt2][j] + bb2;
                    v = v * osc_i[rI] + osh_i[rI];
                    out[((size_t)bb * 192 + tt * 24 + col) * 128 + f] = v;
                }
            }
        }
    }
}

extern "C" void kernel_launch(void* const* d_in, const int* in_sizes, int n_in,
                              void* d_out, int out_size, void* d_ws, size_t ws_size,
                              hipStream_t stream) {
    (void)in_sizes; (void)n_in; (void)out_size; (void)ws_size;
    const float* x          = (const float*)d_in[0];
    const float* revin_w    = (const float*)d_in[1];
    const float* revin_b    = (const float*)d_in[2];
    const float* W_enc      = (const float*)d_in[3];
    const float* b_enc      = (const float*)d_in[4];
    const float* W_vel      = (const float*)d_in[5];
    const float* b_vel      = (const float*)d_in[6];
    const float* step_sizes = (const float*)d_in[7];
    const float* W1         = (const float*)d_in[8];
    const float* b1         = (const float*)d_in[9];
    const float* W2         = (const float*)d_in[10];
    const float* b2         = (const float*)d_in[11];
    float* out = (float*)d_out;

    float* wsf   = (float*)d_ws;
    float* sc    = wsf;                          // 16384
    float* sh    = sc + 16384;
    float* osc   = sh + 16384;
    float* osh   = osc + 16384;
    float* z0    = osh + 16384;                  // 16384*128
    float* vinit = z0 + (size_t)16384 * 128;
    float* mx    = vinit + (size_t)16384 * 128;
    float* cvec  = mx + (size_t)16384 * 128;     // 128
    float* scp   = cvec + 128;                   // 64 (pad)
    ushort* W1t  = (ushort*)(scp + 64);          // 32768
    ushort* W2tp = W1t + 32768;                  // 8192
    ushort* ub   = W2tp + 8192;                  // 229376*128 bf16 (58.7MB)
    ushort* tanb = ub;                           // aliased: ub dead before k_future writes

    k_prep<<<dim3(161), dim3(256), 0, stream>>>(W1, W2, b_vel, W1t, W2tp, cvec, scp);
    k_stats<<<dim3(128), dim3(1024), 0, stream>>>(x, revin_w, revin_b, sc, sh, osc, osh);
    k_u<<<dim3(1792), dim3(256), 0, stream>>>(x, sc, sh, W_enc, b_enc, ub);
    k_encode<<<dim3(4096), dim3(256), 0, stream>>>(ub, z0, vinit);
    k_matvec<<<dim3(2048), dim3(256), 0, stream>>>(vinit, W_vel, mx);
    k_future<<<dim3(4096), dim3(256), 0, stream>>>(z0, vinit, mx, cvec, scp, step_sizes, tanb);
    k_head<<<dim3(1024), dim3(256), 0, stream>>>(tanb, W1t, b1, W2tp, b2, osc, osh, out);
}

// Round 5
// 165.267 us; speedup vs baseline: 4.2979x; 1.1688x over previous
//
#include <hip/hip_runtime.h>
#include <hip/hip_bf16.h>

#define EPSF 1e-15f
#define MAXNF 0.99999f

typedef __attribute__((ext_vector_type(8))) short short8v;
typedef __attribute__((ext_vector_type(8))) ushort ushort8v;
typedef __attribute__((ext_vector_type(4))) float f32x4;

__device__ __forceinline__ float wave_sum(float v) {
#pragma unroll
    for (int off = 32; off > 0; off >>= 1) v += __shfl_xor(v, off, 64);
    return v;
}
__device__ __forceinline__ float rcpf(float x) { return __builtin_amdgcn_rcpf(x); }
// x >= 0; series guard avoids (1-e) cancellation at small x
__device__ __forceinline__ float tanh_g(float x) {
    if (x < 0.03f) return x * (1.f - 0.33333333f * x * x);
    float e = __expf(-2.f * x);
    return (1.f - e) * rcpf(1.f + e);
}
// 0 <= x <= 1-1e-7
__device__ __forceinline__ float atanh_g(float x) {
    if (x < 0.03f) return x * (1.f + 0.33333333f * x * x);
    return 0.5f * __logf((1.f + x) * rcpf(1.f - x));
}
__device__ __forceinline__ ushort f2bf(float f) {
    uint32_t u = __float_as_uint(f);
    uint32_t r = (u + 0x7fffu + ((u >> 16) & 1u)) >> 16;
    return (ushort)r;
}
__device__ __forceinline__ float bf2f(ushort u) { return __uint_as_float(((uint32_t)u) << 16); }

// ---------------- K0: prep — W1^T/W2^T to bf16, c = expmap0(b_vel) ----------------
__global__ __launch_bounds__(256) void k_prep(
    const float* __restrict__ W1, const float* __restrict__ W2,
    const float* __restrict__ b_vel,
    ushort* __restrict__ W1t, ushort* __restrict__ W2tp,
    float* __restrict__ cvec, float* __restrict__ scp) {
    int bid = blockIdx.x, tid = threadIdx.x;
    if (bid == 0) {
        __shared__ float red[4];
        float v = (tid < 128) ? b_vel[tid] : 0.f;
        float p = wave_sum(v * v);
        if ((tid & 63) == 0) red[tid >> 6] = p;
        __syncthreads();
        float ssq = red[0] + red[1] + red[2] + red[3];
        float nn = sqrtf(fmaxf(ssq, EPSF));
        float th = tanhf(nn);
        if (tid < 128) cvec[tid] = th / nn * v;
        if (tid == 0) scp[0] = th * th;
    } else if (bid <= 128) {
        int idx = (bid - 1) * 256 + tid;      // n*128 + k
        int n = idx >> 7, k = idx & 127;
        W1t[idx] = f2bf(W1[k * 256 + n]);
    } else {
        int idx = (bid - 129) * 256 + tid;    // s*256 + j  (s padded to 32)
        int s = idx >> 8, j = idx & 255;
        W2tp[idx] = (s < 24) ? f2bf(W2[j * 24 + s]) : (ushort)0;
    }
}

// ---------------- K1: RevIN stats -> norm coeffs (sc,sh) + denorm coeffs (osc,osh) ----------------
__global__ __launch_bounds__(1024) void k_stats(
    const float* __restrict__ x, const float* __restrict__ revin_w, const float* __restrict__ revin_b,
    float* __restrict__ sc_o, float* __restrict__ sh_o,
    float* __restrict__ osc_o, float* __restrict__ osh_o) {
    __shared__ float ps[8][128], ps2[8][128];
    int b = blockIdx.x, tid = threadIdx.x;
    int f = tid & 127, half = tid >> 7;   // 8 L-slices of 42
    const float* xp = x + ((size_t)b * 336 + half * 42) * 128 + f;
    float s = 0.f, s2 = 0.f;
    for (int l = 0; l < 42; ++l) { float v = xp[(size_t)l * 128]; s += v; s2 += v * v; }
    ps[half][f] = s; ps2[half][f] = s2;
    __syncthreads();
    if (tid < 128) {
        float S = 0.f, S2 = 0.f;
#pragma unroll
        for (int h = 0; h < 8; ++h) { S += ps[h][f]; S2 += ps2[h][f]; }
        float m = S * (1.f / 336.f);
        float var = S2 * (1.f / 336.f) - m * m;
        float sd = sqrtf(var + 1e-5f);
        int r = b * 128 + f;
        float rw = revin_w[f], rb = revin_b[f];
        float sc = rw * rcpf(sd);
        sc_o[r] = sc;
        sh_o[r] = rb - m * sc;
        float oc = sd * rcpf(rw);
        osc_o[r] = oc;
        osh_o[r] = m - rb * oc;
    }
}

// ---------------- K2: u = xn_seg @ W_enc + b_enc  (fp32 GEMM, out bf16) ----------------
__global__ __launch_bounds__(256) void k_u(
    const float* __restrict__ x, const float* __restrict__ sc_i, const float* __restrict__ sh_i,
    const float* __restrict__ W_enc, const float* __restrict__ b_enc,
    ushort* __restrict__ ub) {
    __shared__ float xs[24][132];
    __shared__ float ws[24][192];   // 8-float chunks at stride 12 (2-way banks, free)
    int bid = blockIdx.x;
    int b = bid / 14, n = bid - b * 14;
    int tid = threadIdx.x;
    for (int e = tid; e < 24 * 128; e += 256) {
        int s = e >> 7, f = e & 127;
        xs[s][f] = x[((size_t)b * 336 + n * 24 + s) * 128 + f] * sc_i[b * 128 + f] + sh_i[b * 128 + f];
        ws[s][(f >> 3) * 12 + (f & 7)] = W_enc[s * 128 + f];
    }
    __syncthreads();
    int dchunk = tid & 15, fg = tid >> 4;
    int d0 = dchunk * 8, f0 = fg * 8;
    float acc[8][8];
#pragma unroll
    for (int i = 0; i < 8; ++i)
#pragma unroll
        for (int j = 0; j < 8; ++j) acc[i][j] = 0.f;
#pragma unroll
    for (int s = 0; s < 24; ++s) {
        f32x4 xa = *(const f32x4*)&xs[s][f0];
        f32x4 xb2 = *(const f32x4*)&xs[s][f0 + 4];
        f32x4 wa = *(const f32x4*)&ws[s][dchunk * 12];
        f32x4 wb = *(const f32x4*)&ws[s][dchunk * 12 + 4];
        float xv[8], wv[8];
#pragma unroll
        for (int q = 0; q < 4; ++q) { xv[q] = xa[q]; xv[q + 4] = xb2[q]; wv[q] = wa[q]; wv[q + 4] = wb[q]; }
#pragma unroll
        for (int i = 0; i < 8; ++i)
#pragma unroll
            for (int j = 0; j < 8; ++j) acc[i][j] += xv[i] * wv[j];
    }
    float bj[8];
#pragma unroll
    for (int j = 0; j < 8; ++j) bj[j] = b_enc[d0 + j];
#pragma unroll
    for (int i = 0; i < 8; ++i) {
        ushort8v o;
#pragma unroll
        for (int j = 0; j < 8; ++j) o[j] = f2bf(acc[i][j] + bj[j]);
        *(ushort8v*)&ub[(((size_t)(b * 128 + f0 + i)) * 14 + n) * 128 + d0] = o;
    }
}

// ---------------- K3: hyperbolic recurrence — MFMA Gram + lane-parallel scalar recurrence ----------------
// Block = 256 threads, 32 rows. Phase A: per-row Gram U·U^T via 4 MFMAs (same frag as A and B).
// Phase B: lane=row recurrence on Gram scalars -> linear coefficients. Phase C: vinit/z0 = coef·U.
__global__ __launch_bounds__(256, 2) void k_encode(
    const ushort* __restrict__ ub,
    float* __restrict__ z0_o, float* __restrict__ vinit_o) {
    __shared__ float gram[32][29];   // [0..13]=ssq, [14+n]=dot(u_{n-1},u_n); stride 29 -> conflict-free
    __shared__ float coef[32][17];   // [0..13]=c_m, [14]=scz_last
    int tid = threadIdx.x;
    int w = tid >> 6, lane = tid & 63;
    int lrow = lane & 15, lk = lane >> 4;
    int rbase = blockIdx.x * 32;

    // Phase A: 8 rows per wave, 2 independent MFMA chains at a time
    for (int i = 0; i < 8; i += 2) {
        int rl0 = w * 8 + i, rl1 = rl0 + 1;
        const ushort* t0 = ub + (size_t)(rbase + rl0) * 1792 + lrow * 128 + lk * 8;
        const ushort* t1 = t0 + 1792;
        short8v a0[4], a1[4];
#pragma unroll
        for (int kk = 0; kk < 4; ++kk) {
            a0[kk] = *(const short8v*)(t0 + kk * 32);
            a1[kk] = *(const short8v*)(t1 + kk * 32);
        }
        f32x4 g0 = (f32x4)(0.f), g1 = (f32x4)(0.f);
#pragma unroll
        for (int kk = 0; kk < 4; ++kk) {
            g0 = __builtin_amdgcn_mfma_f32_16x16x32_bf16(a0[kk], a0[kk], g0, 0, 0, 0);
            g1 = __builtin_amdgcn_mfma_f32_16x16x32_bf16(a1[kk], a1[kk], g1, 0, 0, 0);
        }
#pragma unroll
        for (int j = 0; j < 4; ++j) {
            int crow = lk * 4 + j, ccol = lrow;
            if (crow == ccol && crow < 14) { gram[rl0][crow] = g0[j]; gram[rl1][crow] = g1[j]; }
            if (crow + 1 == ccol && ccol < 14) { gram[rl0][14 + ccol] = g0[j]; gram[rl1][14 + ccol] = g1[j]; }
        }
    }
    __syncthreads();

    // Phase B: 32 lanes, 1 row each — scalar recurrence -> linear coefficients
    if (tid < 32) {
        float wsum = 0.f;
        { float p = 1.f; for (int k = 0; k < 13; ++k) { wsum += p; p *= 0.9f; } }
        float wi; { float p = 1.f; for (int k = 0; k < 12; ++k) p *= 0.9f; wi = p / (wsum * 13.f); }
        float c[14];
#pragma unroll
        for (int m = 0; m < 14; ++m) c[m] = 0.f;
        float sczp = 0.f, szp = 0.f;
#pragma unroll
        for (int n = 0; n < 14; ++n) {
            float ssq = gram[tid][n];
            float nn = sqrtf(fmaxf(ssq, EPSF));
            float th = tanh_g(nn);
            float scz, sz;
            if (th > MAXNF) { scz = MAXNF * rcpf(nn); sz = MAXNF * MAXNF; }
            else            { scz = th * rcpf(nn);    sz = th * th; }
            if (n > 0) {
                float dotup = gram[tid][14 + n];
                float xyp = sczp * scz * dotup;            // sum zp.z
                float t2 = 1.f - 2.f * xyp;                // 1 + 2xy, xy = -xyp
                float den = fmaxf(t2 + szp * sz, EPSF);
                float rden = rcpf(den);
                float a1 = t2 + sz, a2 = 1.f - szp;
                float usq = (a1 * a1 * szp - 2.f * a1 * a2 * xyp + a2 * a2 * sz) * (rden * rden);
                float un = sqrtf(fmaxf(usq, EPSF));
                float art = atanh_g(fminf(un, 1.f - 1e-7f));
                float fac = fmaxf(a2, EPSF) * art * rcpf(un) * rden * wi;
                c[n - 1] += -fac * a1 * sczp;
                c[n]     +=  fac * a2 * scz;
                wi *= (1.f / 0.9f);
            }
            sczp = scz; szp = sz;
        }
#pragma unroll
        for (int m = 0; m < 14; ++m) coef[tid][m] = c[m];
        coef[tid][14] = sczp;
    }
    __syncthreads();

    // Phase C: vinit = sum_n c_n * u_n ; z0 = scz_last * u_13  (2 d-elems per lane)
    for (int i = 0; i < 8; ++i) {
        int rl = w * 8 + i;
        int r = rbase + rl;
        float cc[15];
#pragma unroll
        for (int m = 0; m < 15; ++m) cc[m] = coef[rl][m];
        const uint* up32 = (const uint*)(ub + (size_t)r * 1792);
        float v0 = 0.f, v1 = 0.f, za = 0.f, zb = 0.f;
#pragma unroll
        for (int n = 0; n < 14; ++n) {
            uint u = up32[n * 64 + lane];
            float x0 = __uint_as_float(u << 16);
            float x1 = __uint_as_float(u & 0xffff0000u);
            v0 += cc[n] * x0; v1 += cc[n] * x1;
            if (n == 13) { za = cc[14] * x0; zb = cc[14] * x1; }
        }
        size_t ob = (size_t)r * 128 + lane * 2;
        *(float2*)&vinit_o[ob] = make_float2(v0, v1);
        *(float2*)&z0_o[ob] = make_float2(za, zb);
    }
}

// ---------------- K4: mx = v_init @ W_vel^T  (8 rows/block, 4 rows/thread) ----------------
__global__ __launch_bounds__(256) void k_matvec(
    const float* __restrict__ vinit, const float* __restrict__ W_vel,
    float* __restrict__ mx_o) {
    __shared__ float vv[8][128];
    int tid = threadIdx.x;
    int r0 = blockIdx.x * 8;
    for (int i = tid; i < 1024; i += 256) vv[i >> 7][i & 127] = vinit[(size_t)r0 * 128 + i];
    __syncthreads();
    int d = tid & 127, h = tid >> 7;
    float m0 = 0.f, m1 = 0.f, m2 = 0.f, m3 = 0.f;
    const float4* wr = reinterpret_cast<const float4*>(W_vel + (size_t)d * 128);
    const float4* v0 = reinterpret_cast<const float4*>(vv[h * 4 + 0]);
    const float4* v1 = reinterpret_cast<const float4*>(vv[h * 4 + 1]);
    const float4* v2 = reinterpret_cast<const float4*>(vv[h * 4 + 2]);
    const float4* v3 = reinterpret_cast<const float4*>(vv[h * 4 + 3]);
#pragma unroll 8
    for (int j = 0; j < 32; ++j) {
        float4 w = wr[j];
        float4 a = v0[j]; m0 += w.x * a.x + w.y * a.y + w.z * a.z + w.w * a.w;
        float4 bb = v1[j]; m1 += w.x * bb.x + w.y * bb.y + w.z * bb.z + w.w * bb.w;
        float4 c = v2[j]; m2 += w.x * c.x + w.y * c.y + w.z * c.z + w.w * c.w;
        float4 e = v3[j]; m3 += w.x * e.x + w.y * e.y + w.z * e.z + w.w * e.w;
    }
    mx_o[(size_t)(r0 + h * 4 + 0) * 128 + d] = m0;
    mx_o[(size_t)(r0 + h * 4 + 1) * 128 + d] = m1;
    mx_o[(size_t)(r0 + h * 4 + 2) * 128 + d] = m2;
    mx_o[(size_t)(r0 + h * 4 + 3) * 128 + d] = m3;
}

// ---------------- K5: v0t tail + futures -> tan (bf16); t-loop fully scalar ----------------
__global__ __launch_bounds__(256) void k_future(
    const float* __restrict__ z0_i, const float* __restrict__ vinit, const float* __restrict__ mx_i,
    const float* __restrict__ cvec, const float* __restrict__ scp,
    const float* __restrict__ step_sizes, ushort* __restrict__ tanb) {
    int wid = threadIdx.x >> 6, lane = threadIdx.x & 63;
    int r = blockIdx.x * 4 + wid;
    size_t base = (size_t)r * 128;
    float vi0 = vinit[base + lane], vi1 = vinit[base + lane + 64];
    float mx0 = mx_i[base + lane], mx1 = mx_i[base + lane + 64];
    float z00 = z0_i[base + lane], z01 = z0_i[base + lane + 64];
    float c0 = cvec[lane], c1 = cvec[lane + 64];
    float scc = scp[0];
    float xn2  = wave_sum(vi0 * vi0 + vi1 * vi1);
    float mxn2 = wave_sum(mx0 * mx0 + mx1 * mx1);
    float mxc  = wave_sum(mx0 * c0 + mx1 * c1);
    float z0mx = wave_sum(z00 * mx0 + z01 * mx1);
    float z0c  = wave_sum(z00 * c0 + z01 * c1);
    float x2   = wave_sum(z00 * z00 + z01 * z01);
    // mobius_matvec tail: m = scm * mx
    float xn = sqrtf(fmaxf(xn2, EPSF));
    float mxn = sqrtf(fmaxf(mxn2, EPSF));
    float artx = atanh_g(fminf(xn, 1.f - 1e-7f));
    float tm = tanh_g(mxn * rcpf(xn) * artx);
    float scm = tm * rcpf(mxn);
    float sm = tm * tm;
    // mobius_add(m, c) -> v0 = A2*mx + B2*c, then projx
    float xy2 = scm * mxc;
    float den2 = fmaxf(1.f + 2.f * xy2 + sm * scc, EPSF);
    float rd2 = rcpf(den2);
    float A2 = (1.f + 2.f * xy2 + scc) * scm * rd2;
    float B2 = (1.f - sm) * rd2;
    float v0n2 = A2 * A2 * mxn2 + 2.f * A2 * B2 * mxc + B2 * B2 * scc;
    float nv0 = sqrtf(fmaxf(v0n2, EPSF));
    if (nv0 > MAXNF) { float pf = MAXNF * rcpf(nv0); A2 *= pf; B2 *= pf; nv0 = MAXNF; }
    v0n2 = nv0 * nv0;
    float inv_nv0 = rcpf(nv0);
    float zdv = A2 * z0mx + B2 * z0c;            // sum z0.v0
    float v00 = A2 * mx0 + B2 * c0, v01 = A2 * mx1 + B2 * c1;
    float il = rcpf(fmaxf(1.f - x2, EPSF));      // lam/2
    float step = rcpf(1.f + __expf(-step_sizes[0]));
#pragma unroll
    for (int t = 1; t <= 8; ++t) {
        float nt = step * (float)t * nv0;
        float th = tanh_g(nt * il);
        float xy = th * inv_nv0 * zdv;
        float y2 = th * th;
        float den = fmaxf(1.f + 2.f * xy + x2 * y2, EPSF);
        float rd = rcpf(den);
        float A = (1.f + 2.f * xy + y2) * rd;
        float B = (1.f - x2) * th * inv_nv0 * rd;
        float rsq = A * A * x2 + 2.f * A * B * zdv + B * B * v0n2;
        float nr = sqrtf(fmaxf(rsq, EPSF));
        if (nr > MAXNF) { float pf = MAXNF * rcpf(nr); A *= pf; B *= pf; nr = MAXNF; }
        float art = atanh_g(fminf(nr, 1.f - 1e-7f));
        float tf = art * rcpf(nr);
        float FA = tf * A, FB = tf * B;
        size_t ob = ((size_t)r * 8 + (t - 1)) * 128;
        tanb[ob + lane] = f2bf(FA * z00 + FB * v00);
        tanb[ob + lane + 64] = f2bf(FA * z01 + FB * v01);
    }
}

// ---------------- K6: head — N-split waves, B-resident, 2-tile loop ----------------
// grid 1024 x 256. Each block: 2 tiles of 64 rows. Wave w owns GEMM1 cols [w*64,w*64+64).
__global__ __launch_bounds__(256, 2) void k_head(
    const ushort* __restrict__ tanb, const ushort* __restrict__ W1t, const float* __restrict__ b1,
    const ushort* __restrict__ W2tp, const float* __restrict__ b2,
    const float* __restrict__ osc_i, const float* __restrict__ osh_i,
    float* __restrict__ out) {
    __shared__ __align__(16) ushort hs[64][264];
    int wid = threadIdx.x >> 6, lane = threadIdx.x & 63;
    int lrow = lane & 15, lk = lane >> 4;

    // persistent GEMM1 B-frags: this wave's 64 N-cols (loaded once)
    short8v Bw[4][4];
#pragma unroll
    for (int nt = 0; nt < 4; ++nt) {
        const ushort* wp = W1t + (size_t)((wid * 4 + nt) * 16 + lrow) * 128 + lk * 8;
#pragma unroll
        for (int kk = 0; kk < 4; ++kk) Bw[nt][kk] = *(const short8v*)(wp + kk * 32);
    }
    float b1v[4];
#pragma unroll
    for (int nt = 0; nt < 4; ++nt) b1v[nt] = b1[(wid * 4 + nt) * 16 + lrow];
    float b2a = (lrow < 24) ? b2[lrow] : 0.f;          // nt2=0 cols
    float b2bv = (lrow < 8) ? b2[16 + lrow] : 0.f;     // nt2=1 cols

    int tile0 = blockIdx.x * 2;
    // preload A for tile 0 (64 rows: 4 row-groups x 4 k-chunks)
    short8v A[4][4];
    {
        const ushort* tp = tanb + ((size_t)tile0 * 64 + lrow) * 128 + lk * 8;
#pragma unroll
        for (int rg = 0; rg < 4; ++rg)
#pragma unroll
            for (int kk = 0; kk < 4; ++kk)
                A[rg][kk] = *(const short8v*)(tp + (size_t)rg * 2048 + kk * 32);
    }
#pragma unroll
    for (int it = 0; it < 2; ++it) {
        int r0 = (tile0 + it) * 64;
        f32x4 acc[4][4];
#pragma unroll
        for (int rg = 0; rg < 4; ++rg)
#pragma unroll
            for (int nt = 0; nt < 4; ++nt) acc[rg][nt] = (f32x4)(0.f);
#pragma unroll
        for (int kk = 0; kk < 4; ++kk)
#pragma unroll
            for (int rg = 0; rg < 4; ++rg)
#pragma unroll
                for (int nt = 0; nt < 4; ++nt)
                    acc[rg][nt] = __builtin_amdgcn_mfma_f32_16x16x32_bf16(A[rg][kk], Bw[nt][kk], acc[rg][nt], 0, 0, 0);
        // prefetch next tile's A; latency hides under LDS + GEMM2 + epilogue
        if (it + 1 < 2) {
            const ushort* tp = tanb + ((size_t)(tile0 + it + 1) * 64 + lrow) * 128 + lk * 8;
#pragma unroll
            for (int rg = 0; rg < 4; ++rg)
#pragma unroll
                for (int kk = 0; kk < 4; ++kk)
                    A[rg][kk] = *(const short8v*)(tp + (size_t)rg * 2048 + kk * 32);
        }
        __syncthreads();   // protect previous iter's hs reads before overwrite (no-op on it 0)
        // h slice -> LDS: rows rg*16+lk*4+j, col (wid*4+nt)*16+lrow
#pragma unroll
        for (int rg = 0; rg < 4; ++rg)
#pragma unroll
            for (int nt = 0; nt < 4; ++nt)
#pragma unroll
                for (int j = 0; j < 4; ++j)
                    hs[rg * 16 + lk * 4 + j][(wid * 4 + nt) * 16 + lrow] =
                        f2bf(fmaxf(acc[rg][nt][j] + b1v[nt], 0.f));
        __syncthreads();
        // GEMM2: wave computes its 16 rows over full K=256
        f32x4 acc2[2];
        acc2[0] = (f32x4)(0.f); acc2[1] = (f32x4)(0.f);
#pragma unroll
        for (int kk2 = 0; kk2 < 8; ++kk2) {
            short8v Ah = *(const short8v*)&hs[wid * 16 + lrow][kk2 * 32 + lk * 8];
#pragma unroll
            for (int nt2 = 0; nt2 < 2; ++nt2) {
                short8v Bv = *(const short8v*)(W2tp + (size_t)(nt2 * 16 + lrow) * 256 + kk2 * 32 + lk * 8);
                acc2[nt2] = __builtin_amdgcn_mfma_f32_16x16x32_bf16(Ah, Bv, acc2[nt2], 0, 0, 0);
            }
        }
        // epilogue: +b2, denorm, transposed scatter store
#pragma unroll
        for (int nt2 = 0; nt2 < 2; ++nt2) {
            int col = nt2 * 16 + lrow;
            if (col < 24) {
                float bb2 = (nt2 == 0) ? b2a : b2bv;
#pragma unroll
                for (int j = 0; j < 4; ++j) {
                    int row = r0 + wid * 16 + lk * 4 + j;
                    int rI = row >> 3, tt = row & 7;
                    int bb = rI >> 7, f = rI & 127;
                    float v = acc2[nt2][j] + bb2;
                    v = v * osc_i[rI] + osh_i[rI];
                    out[((size_t)bb * 192 + tt * 24 + col) * 128 + f] = v;
                }
            }
        }
    }
}

extern "C" void kernel_launch(void* const* d_in, const int* in_sizes, int n_in,
                              void* d_out, int out_size, void* d_ws, size_t ws_size,
                              hipStream_t stream) {
    (void)in_sizes; (void)n_in; (void)out_size; (void)ws_size;
    const float* x          = (const float*)d_in[0];
    const float* revin_w    = (const float*)d_in[1];
    const float* revin_b    = (const float*)d_in[2];
    const float* W_enc      = (const float*)d_in[3];
    const float* b_enc      = (const float*)d_in[4];
    const float* W_vel      = (const float*)d_in[5];
    const float* b_vel      = (const float*)d_in[6];
    const float* step_sizes = (const float*)d_in[7];
    const float* W1         = (const float*)d_in[8];
    const float* b1         = (const float*)d_in[9];
    const float* W2         = (const float*)d_in[10];
    const float* b2         = (const float*)d_in[11];
    float* out = (float*)d_out;

    float* wsf   = (float*)d_ws;
    float* sc    = wsf;                          // 16384
    float* sh    = sc + 16384;
    float* osc   = sh + 16384;
    float* osh   = osc + 16384;
    float* z0    = osh + 16384;                  // 16384*128
    float* vinit = z0 + (size_t)16384 * 128;
    float* mx    = vinit + (size_t)16384 * 128;
    float* cvec  = mx + (size_t)16384 * 128;     // 128
    float* scp   = cvec + 128;                   // 64 (pad)
    ushort* W1t  = (ushort*)(scp + 64);          // 32768
    ushort* W2tp = W1t + 32768;                  // 8192
    ushort* ub   = W2tp + 8192;                  // 229376*128 bf16 (58.7MB) + 512 pad (frag over-read)
    ushort* tanb = ub;                           // aliased: ub dead before k_future writes

    k_prep<<<dim3(161), dim3(256), 0, stream>>>(W1, W2, b_vel, W1t, W2tp, cvec, scp);
    k_stats<<<dim3(128), dim3(1024), 0, stream>>>(x, revin_w, revin_b, sc, sh, osc, osh);
    k_u<<<dim3(1792), dim3(256), 0, stream>>>(x, sc, sh, W_enc, b_enc, ub);
    k_encode<<<dim3(512), dim3(256), 0, stream>>>(ub, z0, vinit);
    k_matvec<<<dim3(2048), dim3(256), 0, stream>>>(vinit, W_vel, mx);
    k_future<<<dim3(4096), dim3(256), 0, stream>>>(z0, vinit, mx, cvec, scp, step_sizes, tanb);
    k_head<<<dim3(1024), dim3(256), 0, stream>>>(tanb, W1t, b1, W2tp, b2, osc, osh, out);
}